// Round 19
// baseline (418.838 us; speedup 1.0000x reference)
//
#include <hip/hip_runtime.h>
#include <hip/hip_fp16.h>

#define N_NODES 100000
#define N_EDGES 3200000
#define F_IN 128
#define HID 64
#define N_CLASS 40
#define ZROW N_NODES       // sentinel zero-row index

#define NBUCK 196          // ceil(100000/512)
#define BSHIFT 9
#define NBLK_A 512
#define CHUNK_A ((N_EDGES + NBLK_A - 1) / NBLK_A)

typedef float f32x2 __attribute__((ext_vector_type(2)));

static __device__ __forceinline__ unsigned char enc_fp8(float v) {
    return (unsigned char)(__builtin_amdgcn_cvt_pk_fp8_f32(v, v, 0, false) & 0xff);
}

// gather 8 fp8 bytes: byteoff = row<<6 (pre-shifted), seg in [0,8)
static __device__ __forceinline__ uint2 gat8(const unsigned char* base, int byteoff, int seg) {
    return *(const uint2*)(base + ((unsigned)byteoff | (unsigned)(seg << 3)));
}

// decode 8 fp8 (uint2), packed-f32 accumulate
#define CONS(RAW) do { \
    f32x2 f0 = __builtin_amdgcn_cvt_pk_f32_fp8((int)RAW.x, false); \
    f32x2 f1 = __builtin_amdgcn_cvt_pk_f32_fp8((int)RAW.x, true); \
    f32x2 f2 = __builtin_amdgcn_cvt_pk_f32_fp8((int)RAW.y, false); \
    f32x2 f3 = __builtin_amdgcn_cvt_pk_f32_fp8((int)RAW.y, true); \
    a01 += f0; a23 += f1; a45 += f2; a67 += f3; } while (0)

// pipelined slot: issue gather for ib=bb+6+s using idx C (loaded last pass),
// reload C for pass+2, consume G
#define SLOT(s, G, C) { \
    int ib = bb + 6 + s; \
    int srcr = (ib < nb) ? C : zb; \
    uint2 ng = gat8(gsrc, srcr, seg); \
    C = sp[bb * 8 + 96 + s * 8]; \
    __builtin_amdgcn_sched_barrier(0); \
    CONS(G); \
    G = ng; }

// gather phase: accumulate over all in-edges into a01..a67, reduce across e-groups.
// after this, e==0 lanes hold features seg*8+0..7 in a01..a67.
#define GATHER_PHASE(TBL) \
    f32x2 a01 = {0.f, 0.f}, a23 = {0.f, 0.f}, a45 = {0.f, 0.f}, a67 = {0.f, 0.f}; \
    { \
        const unsigned char* gsrc = TBL; \
        int nb = pdeg[node] >> 3; \
        const int* sp = srow + start + e; \
        const int zb = ZROW << 6; \
        if (nb > 0) { \
            int c0 = sp[0],  c1 = sp[8],  c2 = sp[16], c3 = sp[24], c4 = sp[32], c5 = sp[40]; \
            uint2 g0 = gat8(gsrc, (0 < nb) ? c0 : zb, seg); \
            uint2 g1 = gat8(gsrc, (1 < nb) ? c1 : zb, seg); \
            uint2 g2 = gat8(gsrc, (2 < nb) ? c2 : zb, seg); \
            uint2 g3 = gat8(gsrc, (3 < nb) ? c3 : zb, seg); \
            uint2 g4 = gat8(gsrc, (4 < nb) ? c4 : zb, seg); \
            uint2 g5 = gat8(gsrc, (5 < nb) ? c5 : zb, seg); \
            c0 = sp[48]; c1 = sp[56]; c2 = sp[64]; c3 = sp[72]; c4 = sp[80]; c5 = sp[88]; \
            for (int bb = 0; bb < nb; bb += 6) { \
                SLOT(0, g0, c0) SLOT(1, g1, c1) SLOT(2, g2, c2) \
                SLOT(3, g3, c3) SLOT(4, g4, c4) SLOT(5, g5, c5) \
            } \
        } \
        if (e == 0) {  /* self term, counted once */ \
            uint2 sg = gat8(gsrc, node << 6, seg); \
            CONS(sg); \
        } \
    } \
    _Pragma("unroll") \
    for (int mm = 8; mm < 64; mm <<= 1) { \
        a01.x += __shfl_xor(a01.x, mm); a01.y += __shfl_xor(a01.y, mm); \
        a23.x += __shfl_xor(a23.x, mm); a23.y += __shfl_xor(a23.y, mm); \
        a45.x += __shfl_xor(a45.x, mm); a45.y += __shfl_xor(a45.y, mm); \
        a67.x += __shfl_xor(a67.x, mm); a67.y += __shfl_xor(a67.y, mm); \
    }

// ---------------- Phase A1: per-block bucket histogram (transposed out) ----------------
__global__ __launch_bounds__(256) void k_A1(const int* __restrict__ col, int* __restrict__ ghistT) {
    __shared__ int hist[256];
    int t = threadIdx.x;
    hist[t] = 0;
    __syncthreads();
    int e0 = blockIdx.x * CHUNK_A;
    int e1 = e0 + CHUNK_A; if (e1 > N_EDGES) e1 = N_EDGES;
    for (int e = e0 + t; e < e1; e += 256) {
        atomicAdd(&hist[col[e] >> BSHIFT], 1);
    }
    __syncthreads();
    ghistT[t * NBLK_A + blockIdx.x] = hist[t];
}

// ---------------- Phase A2a: per-bucket scan over 512 A-blocks ----------------
__global__ __launch_bounds__(256) void k_A2a(const int* __restrict__ ghistT, int* __restrict__ goffT,
                                             int* __restrict__ tot) {
    __shared__ int s[256];
    int b = blockIdx.x, t = threadIdx.x;
    int2 v = ((const int2*)(ghistT + b * NBLK_A))[t];
    int pair = v.x + v.y;
    s[t] = pair;
    __syncthreads();
    for (int d = 1; d < 256; d <<= 1) {
        int o = (t >= d) ? s[t - d] : 0;
        __syncthreads();
        s[t] += o;
        __syncthreads();
    }
    int incl = s[t];
    int excl = incl - pair;
    goffT[b * NBLK_A + 2 * t]     = excl;
    goffT[b * NBLK_A + 2 * t + 1] = excl + v.x;
    if (t == 255) tot[b] = incl;
}

// ---------------- Phase A2b: scan of bucket totals + sentinel zero + padded b2 ----------------
__global__ __launch_bounds__(256) void k_A2b(const int* __restrict__ tot, int* __restrict__ bbase,
                                             int* __restrict__ bend,
                                             unsigned char* __restrict__ h1q,
                                             unsigned char* __restrict__ h2q,
                                             const float* __restrict__ b2, float* __restrict__ pb2) {
    __shared__ int s[256];
    int t = threadIdx.x;
    int v = tot[t];
    s[t] = v;
    __syncthreads();
    for (int d = 1; d < 256; d <<= 1) {
        int o = (t >= d) ? s[t - d] : 0;
        __syncthreads();
        s[t] += o;
        __syncthreads();
    }
    bbase[t] = s[t] - v;
    bend[t] = s[t];
    if (t < 64) h1q[(size_t)ZROW * 64 + t] = 0;
    else if (t < 128) h2q[(size_t)ZROW * 64 + (t - 64)] = 0;
    else if (t < 192) pb2[t - 128] = (t - 128 < N_CLASS) ? b2[t - 128] : 0.f;
}

// ---------------- Phase A3: coalesced-reserved bucket scatter ----------------
__global__ __launch_bounds__(256) void k_A3(const int* __restrict__ row, const int* __restrict__ col,
                                            const int* __restrict__ goffT, const int* __restrict__ bbase,
                                            unsigned int* __restrict__ epair) {
    __shared__ int cur[256];
    int t = threadIdx.x;
    cur[t] = goffT[t * NBLK_A + blockIdx.x] + bbase[t];
    __syncthreads();
    int e0 = blockIdx.x * CHUNK_A;
    int e1 = e0 + CHUNK_A; if (e1 > N_EDGES) e1 = N_EDGES;
    for (int e = e0 + t; e < e1; e += 256) {
        int c = col[e];
        int pos = atomicAdd(&cur[c >> BSHIFT], 1);
        epair[pos] = ((unsigned int)(c & 511) << 17) | (unsigned int)row[e];
    }
}

// ---------------- Phase B: per-bucket CSR build; srow holds (row<<6) byte offsets ----------------
__global__ __launch_bounds__(256) void k_B(const unsigned int* __restrict__ epair,
                                           const int* __restrict__ bbase, const int* __restrict__ bend,
                                           int* __restrict__ off, int* __restrict__ pdeg,
                                           float* __restrict__ dinv, int* __restrict__ srow) {
    __shared__ int h[512];
    __shared__ int psc[256];
    int t = threadIdx.x;
    int b = blockIdx.x;
    int n0 = b << BSHIFT;
    int e0 = bbase[b], e1 = bend[b];
    int pbase = e0 + b * 4096;
    h[t] = 0; h[t + 256] = 0;
    __syncthreads();
    for (int e = e0 + t; e < e1; e += 256) {
        atomicAdd(&h[epair[e] >> 17], 1);
    }
    __syncthreads();
    int a0 = h[2 * t], a1 = h[2 * t + 1];
    int p0 = (a0 + 7) & ~7, p1 = (a1 + 7) & ~7;
    psc[t] = p0 + p1;
    __syncthreads();
    for (int d = 1; d < 256; d <<= 1) {
        int o = (t >= d) ? psc[t - d] : 0;
        __syncthreads();
        psc[t] += o;
        __syncthreads();
    }
    int base0 = pbase + psc[t] - (p0 + p1);
    int base1 = base0 + p0;
    h[2 * t] = base0;
    h[2 * t + 1] = base1;
    int n = n0 + 2 * t;
    const int zb = ZROW << 6;
    if (n < N_NODES) {
        off[n] = base0; pdeg[n] = p0; dinv[n] = rsqrtf((float)a0 + 1.0f);
        for (int p = a0; p < p0; ++p) srow[base0 + p] = zb;
    }
    if (n + 1 < N_NODES) {
        off[n + 1] = base1; pdeg[n + 1] = p1; dinv[n + 1] = rsqrtf((float)a1 + 1.0f);
        for (int p = a1; p < p1; ++p) srow[base1 + p] = zb;
    }
    __syncthreads();
    for (int e = e0 + t; e < e1; e += 256) {
        unsigned int k = epair[e];
        int c = k >> 17;
        int pos = atomicAdd(&h[c], 1);
        srow[pos] = (int)(k & 0x1FFFFu) << 6;
    }
}

// ---------------- tiled dense GEMM (layer 1): h1q = fp8(dinv[n]*(X @ W1^T)) ----------------
template<int K, int C, int ROWS_PB>
__global__ __launch_bounds__(256, 4) void k_gemm(const float* __restrict__ X, const float* __restrict__ W,
                                                 const float* __restrict__ scale, unsigned char* __restrict__ O) {
    constexpr int PK = K + 4;
    __shared__ float ws[C * PK];
    __shared__ float xs[32 * PK];
    int t = threadIdx.x;
    for (int i4 = t; i4 < C * K / 4; i4 += 256) {
        int j = i4 / (K / 4);
        int k4 = i4 % (K / 4);
        float4 v = ((const float4*)W)[i4];
        *(float4*)&ws[j * PK + k4 * 4] = v;
    }
    int j = t & 63;
    int r0 = (t >> 6) * 8;
    int rowbase = blockIdx.x * ROWS_PB;
    for (int chunk = 0; chunk < ROWS_PB; chunk += 32) {
        int cb = rowbase + chunk;
        __syncthreads();
        for (int i4 = t; i4 < 32 * K / 4; i4 += 256) {
            int r = i4 / (K / 4);
            int k4 = i4 % (K / 4);
            int rr = cb + r;
            float4 v = make_float4(0.f, 0.f, 0.f, 0.f);
            if (rr < N_NODES) v = ((const float4*)X)[(size_t)rr * (K / 4) + k4];
            *(float4*)&xs[r * PK + k4 * 4] = v;
        }
        __syncthreads();
        if (j < C) {
            float acc[8] = {0.f, 0.f, 0.f, 0.f, 0.f, 0.f, 0.f, 0.f};
#pragma unroll 2
            for (int k4 = 0; k4 < K / 4; ++k4) {
                float4 wv = *(const float4*)&ws[j * PK + k4 * 4];
#pragma unroll
                for (int r = 0; r < 8; ++r) {
                    float4 xv = *(const float4*)&xs[(r0 + r) * PK + k4 * 4];
                    acc[r] += xv.x * wv.x + xv.y * wv.y + xv.z * wv.z + xv.w * wv.w;
                }
            }
#pragma unroll
            for (int r = 0; r < 8; ++r) {
                int rr = cb + r0 + r;
                if (rr < N_NODES) O[(size_t)rr * 64 + j] = enc_fp8(acc[r] * scale[rr]);
            }
        }
    }
}

// ---------------- layer-2 dense GEMM: h2q = fp8(8 * (o1h @ W2^T)), rows padded to 64 ----------------
__global__ __launch_bounds__(256, 4) void k_gemm2(const __half* __restrict__ o1h, const float* __restrict__ W2,
                                                  unsigned char* __restrict__ h2q) {
    __shared__ float ws2[N_CLASS * 68];
    __shared__ float xs[32 * 68];
    int t = threadIdx.x;
    for (int i = t; i < N_CLASS * HID; i += 256) {
        int c = i >> 6, k = i & 63;
        ws2[c * 68 + k] = W2[i] * 8.f;   // fold output scale
    }
    int j = t & 63;
    int cl = j < N_CLASS ? j : N_CLASS - 1;
    int r0 = (t >> 6) * 8;
    int rowbase = blockIdx.x * 128;
    for (int chunk = 0; chunk < 128; chunk += 32) {
        int cb = rowbase + chunk;
        __syncthreads();
        {
            int r = t >> 3, k8 = t & 7;
            int rr = cb + r;
            uint4 rawh = make_uint4(0u, 0u, 0u, 0u);
            if (rr < N_NODES) rawh = *(const uint4*)(o1h + (size_t)rr * 64 + k8 * 8);
            __half2* hp = (__half2*)&rawh;
            float2 f0 = __half22float2(hp[0]);
            float2 f1 = __half22float2(hp[1]);
            float2 f2 = __half22float2(hp[2]);
            float2 f3 = __half22float2(hp[3]);
            *(float4*)&xs[r * 68 + k8 * 8]     = make_float4(f0.x, f0.y, f1.x, f1.y);
            *(float4*)&xs[r * 68 + k8 * 8 + 4] = make_float4(f2.x, f2.y, f3.x, f3.y);
        }
        __syncthreads();
        float acc[8] = {0.f, 0.f, 0.f, 0.f, 0.f, 0.f, 0.f, 0.f};
#pragma unroll 2
        for (int k4 = 0; k4 < HID / 4; ++k4) {
            float4 wv = *(const float4*)&ws2[cl * 68 + k4 * 4];
#pragma unroll
            for (int r = 0; r < 8; ++r) {
                float4 xv = *(const float4*)&xs[(r0 + r) * 68 + k4 * 4];
                acc[r] += xv.x * wv.x + xv.y * wv.y + xv.z * wv.z + xv.w * wv.w;
            }
        }
#pragma unroll
        for (int r = 0; r < 8; ++r) {
            int rr = cb + r0 + r;
            if (rr < N_NODES) h2q[(size_t)rr * 64 + j] = (j < N_CLASS) ? enc_fp8(acc[r]) : (unsigned char)0;
        }
    }
}

// ---------------- layer-1 aggregation: gather h1q -> o1h fp16 (dinv*relu) ----------------
__global__ __launch_bounds__(256) void k_agg1(const int* __restrict__ off, const int* __restrict__ pdeg,
                                              const int* __restrict__ srow, const float* __restrict__ dinv,
                                              const unsigned char* __restrict__ h1q, const float* __restrict__ b1,
                                              __half* __restrict__ o1h) {
    int t = threadIdx.x;
    int node = (blockIdx.x * 256 + t) >> 6;
    int lane = t & 63;
    int e = lane >> 3, seg = lane & 7;
    int start = off[node];
    GATHER_PHASE(h1q)
    if (e == 0) {
        float dc = dinv[node];
        float4 ba = *(const float4*)(b1 + seg * 8);
        float4 bb4 = *(const float4*)(b1 + seg * 8 + 4);
        float v0 = dc * a01.x + ba.x,  v1 = dc * a01.y + ba.y;
        float v2 = dc * a23.x + ba.z,  v3 = dc * a23.y + ba.w;
        float v4 = dc * a45.x + bb4.x, v5 = dc * a45.y + bb4.y;
        float v6 = dc * a67.x + bb4.z, v7 = dc * a67.y + bb4.w;
        v0 = v0 > 0.f ? v0 * dc : 0.f; v1 = v1 > 0.f ? v1 * dc : 0.f;
        v2 = v2 > 0.f ? v2 * dc : 0.f; v3 = v3 > 0.f ? v3 * dc : 0.f;
        v4 = v4 > 0.f ? v4 * dc : 0.f; v5 = v5 > 0.f ? v5 * dc : 0.f;
        v6 = v6 > 0.f ? v6 * dc : 0.f; v7 = v7 > 0.f ? v7 * dc : 0.f;
        __half hh[8];
        hh[0] = __float2half(v0); hh[1] = __float2half(v1);
        hh[2] = __float2half(v2); hh[3] = __float2half(v3);
        hh[4] = __float2half(v4); hh[5] = __float2half(v5);
        hh[6] = __float2half(v6); hh[7] = __float2half(v7);
        *(uint4*)(o1h + ((size_t)node * 64 + seg * 8)) = *(uint4*)hh;
    }
}

// ---------------- layer-2 aggregation: gather h2q + 8-lane softmax/argmax ----------------
__global__ __launch_bounds__(256) void k_agg2(const int* __restrict__ off, const int* __restrict__ pdeg,
                                              const int* __restrict__ srow, const float* __restrict__ dinv,
                                              const unsigned char* __restrict__ h2q,
                                              const float* __restrict__ pb2, const int* __restrict__ y,
                                              float* __restrict__ out, unsigned short* __restrict__ ps) {
    int t = threadIdx.x;
    int node = (blockIdx.x * 256 + t) >> 6;
    int lane = t & 63;
    int e = lane >> 3, seg = lane & 7;
    int start = off[node];
    GATHER_PHASE(h2q)
    if (e == 0) {
        float dc = dinv[node] * 0.125f;   // undo the x8 h2q scale
        float4 ba = *(const float4*)(pb2 + seg * 8);
        float4 bb4 = *(const float4*)(pb2 + seg * 8 + 4);
        bool act = seg < 5;               // classes seg*8..seg*8+7, 40 = 5*8 exactly
        float v0 = act ? (dc * a01.x + ba.x)  : -1e30f;
        float v1 = act ? (dc * a01.y + ba.y)  : -1e30f;
        float v2 = act ? (dc * a23.x + ba.z)  : -1e30f;
        float v3 = act ? (dc * a23.y + ba.w)  : -1e30f;
        float v4 = act ? (dc * a45.x + bb4.x) : -1e30f;
        float v5 = act ? (dc * a45.y + bb4.y) : -1e30f;
        float v6 = act ? (dc * a45.x, dc * a45.x) : -1e30f;  // placeholder fixed below
        v6 = act ? (dc * a67.x + bb4.z) : -1e30f;
        float v7 = act ? (dc * a67.y + bb4.w) : -1e30f;
        // per-lane max + first-occurrence argmax
        float m = v0; int aj = 0;
        if (v1 > m) { m = v1; aj = 1; }
        if (v2 > m) { m = v2; aj = 2; }
        if (v3 > m) { m = v3; aj = 3; }
        if (v4 > m) { m = v4; aj = 4; }
        if (v5 > m) { m = v5; aj = 5; }
        if (v6 > m) { m = v6; aj = 6; }
        if (v7 > m) { m = v7; aj = 7; }
        int ac = seg * 8 + aj;
#pragma unroll
        for (int k = 1; k < 8; k <<= 1) {   // reduce across lanes 0..7
            float om = __shfl_xor(m, k);
            int oc = __shfl_xor(ac, k);
            if (om > m || (om == m && oc < ac)) { m = om; ac = oc; }
        }
        float s = 0.f;
        if (act) {
            s = expf(v0 - m) + expf(v1 - m) + expf(v2 - m) + expf(v3 - m)
              + expf(v4 - m) + expf(v5 - m) + expf(v6 - m) + expf(v7 - m);
        }
#pragma unroll
        for (int k = 1; k < 8; k <<= 1) s += __shfl_xor(s, k);
        float ls = logf(s);
        if (act) {
            float lp0 = (v0 - m) - ls, lp1 = (v1 - m) - ls, lp2 = (v2 - m) - ls, lp3 = (v3 - m) - ls;
            float lp4 = (v4 - m) - ls, lp5 = (v5 - m) - ls, lp6 = (v6 - m) - ls, lp7 = (v7 - m) - ls;
            float* logp = out + (size_t)node * N_CLASS + seg * 8;
            *(float4*)logp       = make_float4(lp0, lp1, lp2, lp3);
            *(float4*)(logp + 4) = make_float4(lp4, lp5, lp6, lp7);
            float* pp = out + (size_t)N_NODES * N_CLASS + (size_t)node * N_CLASS + seg * 8;
            *(float4*)pp       = make_float4(expf(lp0), expf(lp1), expf(lp2), expf(lp3));
            *(float4*)(pp + 4) = make_float4(expf(lp4), expf(lp5), expf(lp6), expf(lp7));
        }
        if (lane == 0) ps[node] = (unsigned short)((y[node] << 8) | ac);
    }
}

// ---------------- ratio over original edges (8 edges / iter) ----------------
__global__ __launch_bounds__(256) void k_ratio(const int* __restrict__ row, const int* __restrict__ col,
                                               const unsigned short* __restrict__ ps,
                                               unsigned int* __restrict__ cnt) {
    int i = blockIdx.x * 256 + threadIdx.x;
    int stride = gridDim.x * 256;
    unsigned int local = 0;
    for (int e8 = i; e8 < N_EDGES / 8; e8 += stride) {
        int4 ra = ((const int4*)row)[e8 * 2];
        int4 rb = ((const int4*)row)[e8 * 2 + 1];
        int4 ca = ((const int4*)col)[e8 * 2];
        int4 cb = ((const int4*)col)[e8 * 2 + 1];
        unsigned int pa[8], pb[8];
        pa[0] = ps[ra.x]; pa[1] = ps[ra.y]; pa[2] = ps[ra.z]; pa[3] = ps[ra.w];
        pa[4] = ps[rb.x]; pa[5] = ps[rb.y]; pa[6] = ps[rb.z]; pa[7] = ps[rb.w];
        pb[0] = ps[ca.x]; pb[1] = ps[ca.y]; pb[2] = ps[ca.z]; pb[3] = ps[ca.w];
        pb[4] = ps[cb.x]; pb[5] = ps[cb.y]; pb[6] = ps[cb.z]; pb[7] = ps[cb.w];
#pragma unroll
        for (int k = 0; k < 8; ++k) {
            bool sp = (pa[k] & 0xffu) == (pb[k] & 0xffu);
            bool sy = (pa[k] >> 8) == (pb[k] >> 8);
            local += (sp == sy) ? 1u : 0u;
        }
    }
    if (local) atomicAdd(cnt, local);
}

__global__ void k_fin(const unsigned int* __restrict__ cnt, float* __restrict__ out) {
    out[0] = (float)(*cnt) / (float)N_EDGES;
}

extern "C" void kernel_launch(void* const* d_in, const int* in_sizes, int n_in,
                              void* d_out, int out_size, void* d_ws, size_t ws_size,
                              hipStream_t stream) {
    const float* x  = (const float*)d_in[0];
    const int*   ei = (const int*)d_in[1];
    const int*   y  = (const int*)d_in[2];
    const float* W1 = (const float*)d_in[3];
    const float* b1 = (const float*)d_in[4];
    const float* W2 = (const float*)d_in[5];
    const float* b2 = (const float*)d_in[6];

    const int* row = ei;
    const int* col = ei + N_EDGES;

    float* ws = (float*)d_ws;
    // workspace layout (4B units); fp8 tables have N_NODES+1 rows (sentinel)
    unsigned char* h1q = (unsigned char*)ws;               // (N+1)*64 B
    unsigned char* h2q = (unsigned char*)(ws + 1700000);   // (N+1)*64 B
    float* dinv   = ws + 3400000;                   // N
    int*   pdeg   = (int*)(ws + 3500000);           // N
    int*   off    = (int*)(ws + 3600000);           // N
    int*   srow   = (int*)(ws + 3700000);           // padded CSR (~4.0M) + tail slack
    int*   ghistT = (int*)(ws + 7800000);           // 256*512 (bucket-major)
    int*   goffT  = (int*)(ws + 8000000);           // 256*512
    int*   tot    = (int*)(ws + 8150000);           // 256
    int*   bbase  = (int*)(ws + 8200000);           // 256
    int*   bend   = (int*)(ws + 8201000);           // 256
    float* pb2    = ws + 8202000;                   // 64 (padded b2)
    unsigned short* ps = (unsigned short*)(ws + 8210000);  // N ushort
    unsigned int* cnt  = (unsigned int*)(ws + 8300000);
    unsigned int* epair = (unsigned int*)(ws + 8400000);   // E uint32 (ends ~11.6M)
    __half* o1h   = (__half*)(ws + 11700000);       // N*64 halves (12.8 MB)

    float* out = (float*)d_out;

    (void)hipMemsetAsync(cnt, 0, 4, stream);

    const int GEMM_GRID = (N_NODES + 127) / 128;
    const int AGG_GRID = (N_NODES * 64) / 256;      // exact: 25000

    k_A1<<<NBLK_A, 256, 0, stream>>>(col, ghistT);
    k_A2a<<<256, 256, 0, stream>>>(ghistT, goffT, tot);
    k_A2b<<<1, 256, 0, stream>>>(tot, bbase, bend, h1q, h2q, b2, pb2);
    k_A3<<<NBLK_A, 256, 0, stream>>>(row, col, goffT, bbase, epair);
    k_B<<<NBUCK, 256, 0, stream>>>(epair, bbase, bend, off, pdeg, dinv, srow);
    k_gemm<F_IN, HID, 128><<<GEMM_GRID, 256, 0, stream>>>(x, W1, dinv, h1q);
    k_agg1<<<AGG_GRID, 256, 0, stream>>>(off, pdeg, srow, dinv, h1q, b1, o1h);
    k_gemm2<<<GEMM_GRID, 256, 0, stream>>>(o1h, W2, h2q);
    k_agg2<<<AGG_GRID, 256, 0, stream>>>(off, pdeg, srow, dinv, h2q, pb2, y, out, ps);
    k_ratio<<<2048, 256, 0, stream>>>(row, col, ps, cnt);
    k_fin<<<1, 1, 0, stream>>>(cnt, out + (size_t)2 * N_NODES * N_CLASS);
}

// Round 20
// 365.426 us; speedup vs baseline: 1.1462x; 1.1462x over previous
//
#include <hip/hip_runtime.h>
#include <hip/hip_fp16.h>

#define N_NODES 100000
#define N_EDGES 3200000
#define F_IN 128
#define HID 64
#define N_CLASS 40
#define ZROW N_NODES       // sentinel zero-row index

#define NBUCK 196          // ceil(100000/512)
#define BSHIFT 9
#define NBLK_A 512
#define CHUNK_A ((N_EDGES + NBLK_A - 1) / NBLK_A)

typedef float f32x2 __attribute__((ext_vector_type(2)));

static __device__ __forceinline__ unsigned char enc_fp8(float v) {
    return (unsigned char)(__builtin_amdgcn_cvt_pk_fp8_f32(v, v, 0, false) & 0xff);
}

// gather 8 fp8 bytes: byteoff = row<<6 (pre-shifted), seg in [0,8)
static __device__ __forceinline__ uint2 gat8(const unsigned char* base, int byteoff, int seg) {
    return *(const uint2*)(base + ((unsigned)byteoff | (unsigned)(seg << 3)));
}

// decode 8 fp8 (uint2), packed-f32 accumulate
#define CONS(RAW) do { \
    f32x2 f0 = __builtin_amdgcn_cvt_pk_f32_fp8((int)RAW.x, false); \
    f32x2 f1 = __builtin_amdgcn_cvt_pk_f32_fp8((int)RAW.x, true); \
    f32x2 f2 = __builtin_amdgcn_cvt_pk_f32_fp8((int)RAW.y, false); \
    f32x2 f3 = __builtin_amdgcn_cvt_pk_f32_fp8((int)RAW.y, true); \
    a01 += f0; a23 += f1; a45 += f2; a67 += f3; } while (0)

// per-lane pipelined slot: consume G (edge bb+s of MY node), issue edge bb+6+s,
// reload C with idx for edge bb+12+s (address clamped to my range)
#define SLOTP(s, G, C) { \
    int ib = bb + 6 + s; \
    int srcr = (ib < mydeg) ? C : zb; \
    uint2 ng = gat8(gsrc, srcr, seg); \
    C = sp[min(bb + 12 + s, mlast)]; \
    __builtin_amdgcn_sched_barrier(0); \
    CONS(G); \
    G = ng; }

// per-lane gather phase: each lane owns node `node` (e-group) and features seg*8..+7.
// No cross-lane reduce needed afterwards.
#define GATHER_PL(TBL) \
    f32x2 a01 = {0.f, 0.f}, a23 = {0.f, 0.f}, a45 = {0.f, 0.f}, a67 = {0.f, 0.f}; \
    { \
        const unsigned char* gsrc = TBL; \
        const int* sp = srow + myoff; \
        const int zb = ZROW << 6; \
        int nbmax = mydeg; \
        nbmax = max(nbmax, __shfl_xor(nbmax, 8)); \
        nbmax = max(nbmax, __shfl_xor(nbmax, 16)); \
        nbmax = max(nbmax, __shfl_xor(nbmax, 32)); \
        if (nbmax > 0) { \
            int mlast = mydeg > 0 ? mydeg - 1 : 0; \
            uint2 g0 = gat8(gsrc, (0 < mydeg) ? sp[0] : zb, seg); \
            uint2 g1 = gat8(gsrc, (1 < mydeg) ? sp[min(1, mlast)] : zb, seg); \
            uint2 g2 = gat8(gsrc, (2 < mydeg) ? sp[min(2, mlast)] : zb, seg); \
            uint2 g3 = gat8(gsrc, (3 < mydeg) ? sp[min(3, mlast)] : zb, seg); \
            uint2 g4 = gat8(gsrc, (4 < mydeg) ? sp[min(4, mlast)] : zb, seg); \
            uint2 g5 = gat8(gsrc, (5 < mydeg) ? sp[min(5, mlast)] : zb, seg); \
            int c0 = sp[min(6, mlast)],  c1 = sp[min(7, mlast)],  c2 = sp[min(8, mlast)]; \
            int c3 = sp[min(9, mlast)], c4 = sp[min(10, mlast)], c5 = sp[min(11, mlast)]; \
            for (int bb = 0; bb < nbmax; bb += 6) { \
                SLOTP(0, g0, c0) SLOTP(1, g1, c1) SLOTP(2, g2, c2) \
                SLOTP(3, g3, c3) SLOTP(4, g4, c4) SLOTP(5, g5, c5) \
            } \
        } \
        /* self term: every lane adds its own node's segment once */ \
        uint2 sg = gat8(gsrc, node << 6, seg); \
        CONS(sg); \
    }

// ---------------- Phase A1: per-block bucket histogram (transposed out) ----------------
__global__ __launch_bounds__(256) void k_A1(const int* __restrict__ col, int* __restrict__ ghistT) {
    __shared__ int hist[256];
    int t = threadIdx.x;
    hist[t] = 0;
    __syncthreads();
    int e0 = blockIdx.x * CHUNK_A;
    int e1 = e0 + CHUNK_A; if (e1 > N_EDGES) e1 = N_EDGES;
    for (int e = e0 + t; e < e1; e += 256) {
        atomicAdd(&hist[col[e] >> BSHIFT], 1);
    }
    __syncthreads();
    ghistT[t * NBLK_A + blockIdx.x] = hist[t];
}

// ---------------- Phase A2a: per-bucket scan over 512 A-blocks ----------------
__global__ __launch_bounds__(256) void k_A2a(const int* __restrict__ ghistT, int* __restrict__ goffT,
                                             int* __restrict__ tot) {
    __shared__ int s[256];
    int b = blockIdx.x, t = threadIdx.x;
    int2 v = ((const int2*)(ghistT + b * NBLK_A))[t];
    int pair = v.x + v.y;
    s[t] = pair;
    __syncthreads();
    for (int d = 1; d < 256; d <<= 1) {
        int o = (t >= d) ? s[t - d] : 0;
        __syncthreads();
        s[t] += o;
        __syncthreads();
    }
    int incl = s[t];
    int excl = incl - pair;
    goffT[b * NBLK_A + 2 * t]     = excl;
    goffT[b * NBLK_A + 2 * t + 1] = excl + v.x;
    if (t == 255) tot[b] = incl;
}

// ---------------- Phase A2b: scan of bucket totals + sentinel zero + padded b2 ----------------
__global__ __launch_bounds__(256) void k_A2b(const int* __restrict__ tot, int* __restrict__ bbase,
                                             int* __restrict__ bend,
                                             unsigned char* __restrict__ h1q,
                                             unsigned char* __restrict__ h2q,
                                             const float* __restrict__ b2, float* __restrict__ pb2) {
    __shared__ int s[256];
    int t = threadIdx.x;
    int v = tot[t];
    s[t] = v;
    __syncthreads();
    for (int d = 1; d < 256; d <<= 1) {
        int o = (t >= d) ? s[t - d] : 0;
        __syncthreads();
        s[t] += o;
        __syncthreads();
    }
    bbase[t] = s[t] - v;
    bend[t] = s[t];
    if (t < 64) h1q[(size_t)ZROW * 64 + t] = 0;
    else if (t < 128) h2q[(size_t)ZROW * 64 + (t - 64)] = 0;
    else if (t < 192) pb2[t - 128] = (t - 128 < N_CLASS) ? b2[t - 128] : 0.f;
}

// ---------------- Phase A3: coalesced-reserved bucket scatter ----------------
__global__ __launch_bounds__(256) void k_A3(const int* __restrict__ row, const int* __restrict__ col,
                                            const int* __restrict__ goffT, const int* __restrict__ bbase,
                                            unsigned int* __restrict__ epair) {
    __shared__ int cur[256];
    int t = threadIdx.x;
    cur[t] = goffT[t * NBLK_A + blockIdx.x] + bbase[t];
    __syncthreads();
    int e0 = blockIdx.x * CHUNK_A;
    int e1 = e0 + CHUNK_A; if (e1 > N_EDGES) e1 = N_EDGES;
    for (int e = e0 + t; e < e1; e += 256) {
        int c = col[e];
        int pos = atomicAdd(&cur[c >> BSHIFT], 1);
        epair[pos] = ((unsigned int)(c & 511) << 17) | (unsigned int)row[e];
    }
}

// ---------------- Phase B: per-bucket CSR build; srow holds (row<<6) byte offsets ----------------
__global__ __launch_bounds__(256) void k_B(const unsigned int* __restrict__ epair,
                                           const int* __restrict__ bbase, const int* __restrict__ bend,
                                           int* __restrict__ off, int* __restrict__ pdeg,
                                           float* __restrict__ dinv, int* __restrict__ srow) {
    __shared__ int h[512];
    __shared__ int psc[256];
    int t = threadIdx.x;
    int b = blockIdx.x;
    int n0 = b << BSHIFT;
    int e0 = bbase[b], e1 = bend[b];
    int pbase = e0 + b * 4096;
    h[t] = 0; h[t + 256] = 0;
    __syncthreads();
    for (int e = e0 + t; e < e1; e += 256) {
        atomicAdd(&h[epair[e] >> 17], 1);
    }
    __syncthreads();
    int a0 = h[2 * t], a1 = h[2 * t + 1];
    int p0 = (a0 + 7) & ~7, p1 = (a1 + 7) & ~7;
    psc[t] = p0 + p1;
    __syncthreads();
    for (int d = 1; d < 256; d <<= 1) {
        int o = (t >= d) ? psc[t - d] : 0;
        __syncthreads();
        psc[t] += o;
        __syncthreads();
    }
    int base0 = pbase + psc[t] - (p0 + p1);
    int base1 = base0 + p0;
    h[2 * t] = base0;
    h[2 * t + 1] = base1;
    int n = n0 + 2 * t;
    const int zb = ZROW << 6;
    if (n < N_NODES) {
        off[n] = base0; pdeg[n] = p0; dinv[n] = rsqrtf((float)a0 + 1.0f);
        for (int p = a0; p < p0; ++p) srow[base0 + p] = zb;
    }
    if (n + 1 < N_NODES) {
        off[n + 1] = base1; pdeg[n + 1] = p1; dinv[n + 1] = rsqrtf((float)a1 + 1.0f);
        for (int p = a1; p < p1; ++p) srow[base1 + p] = zb;
    }
    __syncthreads();
    for (int e = e0 + t; e < e1; e += 256) {
        unsigned int k = epair[e];
        int c = k >> 17;
        int pos = atomicAdd(&h[c], 1);
        srow[pos] = (int)(k & 0x1FFFFu) << 6;
    }
}

// ---------------- tiled dense GEMM (layer 1): h1q = fp8(dinv[n]*(X @ W1^T)) ----------------
template<int K, int C, int ROWS_PB>
__global__ __launch_bounds__(256, 4) void k_gemm(const float* __restrict__ X, const float* __restrict__ W,
                                                 const float* __restrict__ scale, unsigned char* __restrict__ O) {
    constexpr int PK = K + 4;
    __shared__ float ws[C * PK];
    __shared__ float xs[32 * PK];
    int t = threadIdx.x;
    for (int i4 = t; i4 < C * K / 4; i4 += 256) {
        int j = i4 / (K / 4);
        int k4 = i4 % (K / 4);
        float4 v = ((const float4*)W)[i4];
        *(float4*)&ws[j * PK + k4 * 4] = v;
    }
    int j = t & 63;
    int r0 = (t >> 6) * 8;
    int rowbase = blockIdx.x * ROWS_PB;
    for (int chunk = 0; chunk < ROWS_PB; chunk += 32) {
        int cb = rowbase + chunk;
        __syncthreads();
        for (int i4 = t; i4 < 32 * K / 4; i4 += 256) {
            int r = i4 / (K / 4);
            int k4 = i4 % (K / 4);
            int rr = cb + r;
            float4 v = make_float4(0.f, 0.f, 0.f, 0.f);
            if (rr < N_NODES) v = ((const float4*)X)[(size_t)rr * (K / 4) + k4];
            *(float4*)&xs[r * PK + k4 * 4] = v;
        }
        __syncthreads();
        if (j < C) {
            float acc[8] = {0.f, 0.f, 0.f, 0.f, 0.f, 0.f, 0.f, 0.f};
#pragma unroll 2
            for (int k4 = 0; k4 < K / 4; ++k4) {
                float4 wv = *(const float4*)&ws[j * PK + k4 * 4];
#pragma unroll
                for (int r = 0; r < 8; ++r) {
                    float4 xv = *(const float4*)&xs[(r0 + r) * PK + k4 * 4];
                    acc[r] += xv.x * wv.x + xv.y * wv.y + xv.z * wv.z + xv.w * wv.w;
                }
            }
#pragma unroll
            for (int r = 0; r < 8; ++r) {
                int rr = cb + r0 + r;
                if (rr < N_NODES) O[(size_t)rr * 64 + j] = enc_fp8(acc[r] * scale[rr]);
            }
        }
    }
}

// ---------------- layer-2 dense GEMM: h2q = fp8(8 * (o1h @ W2^T)), rows padded to 64 ----------------
__global__ __launch_bounds__(256, 4) void k_gemm2(const __half* __restrict__ o1h, const float* __restrict__ W2,
                                                  unsigned char* __restrict__ h2q) {
    __shared__ float ws2[N_CLASS * 68];
    __shared__ float xs[32 * 68];
    int t = threadIdx.x;
    for (int i = t; i < N_CLASS * HID; i += 256) {
        int c = i >> 6, k = i & 63;
        ws2[c * 68 + k] = W2[i] * 8.f;   // fold output scale
    }
    int j = t & 63;
    int cl = j < N_CLASS ? j : N_CLASS - 1;
    int r0 = (t >> 6) * 8;
    int rowbase = blockIdx.x * 128;
    for (int chunk = 0; chunk < 128; chunk += 32) {
        int cb = rowbase + chunk;
        __syncthreads();
        {
            int r = t >> 3, k8 = t & 7;
            int rr = cb + r;
            uint4 rawh = make_uint4(0u, 0u, 0u, 0u);
            if (rr < N_NODES) rawh = *(const uint4*)(o1h + (size_t)rr * 64 + k8 * 8);
            __half2* hp = (__half2*)&rawh;
            float2 f0 = __half22float2(hp[0]);
            float2 f1 = __half22float2(hp[1]);
            float2 f2 = __half22float2(hp[2]);
            float2 f3 = __half22float2(hp[3]);
            *(float4*)&xs[r * 68 + k8 * 8]     = make_float4(f0.x, f0.y, f1.x, f1.y);
            *(float4*)&xs[r * 68 + k8 * 8 + 4] = make_float4(f2.x, f2.y, f3.x, f3.y);
        }
        __syncthreads();
        float acc[8] = {0.f, 0.f, 0.f, 0.f, 0.f, 0.f, 0.f, 0.f};
#pragma unroll 2
        for (int k4 = 0; k4 < HID / 4; ++k4) {
            float4 wv = *(const float4*)&ws2[cl * 68 + k4 * 4];
#pragma unroll
            for (int r = 0; r < 8; ++r) {
                float4 xv = *(const float4*)&xs[(r0 + r) * 68 + k4 * 4];
                acc[r] += xv.x * wv.x + xv.y * wv.y + xv.z * wv.z + xv.w * wv.w;
            }
        }
#pragma unroll
        for (int r = 0; r < 8; ++r) {
            int rr = cb + r0 + r;
            if (rr < N_NODES) h2q[(size_t)rr * 64 + j] = (j < N_CLASS) ? enc_fp8(acc[r]) : (unsigned char)0;
        }
    }
}

// ---------------- layer-1 aggregation: 8 nodes/wave, per-lane accumulate, no reduce ----------------
__global__ __launch_bounds__(256) void k_agg1(const int* __restrict__ off, const int* __restrict__ pdeg,
                                              const int* __restrict__ srow, const float* __restrict__ dinv,
                                              const unsigned char* __restrict__ h1q, const float* __restrict__ b1,
                                              __half* __restrict__ o1h) {
    int t = threadIdx.x;
    int lane = t & 63;
    int e = lane >> 3, seg = lane & 7;
    int node = ((blockIdx.x * 256 + t) >> 6) * 8 + e;   // 8 consecutive nodes per wave
    int myoff = off[node];
    int mydeg = pdeg[node];
    GATHER_PL(h1q)
    float dc = dinv[node];
    float4 ba = *(const float4*)(b1 + seg * 8);
    float4 bb4 = *(const float4*)(b1 + seg * 8 + 4);
    float v0 = dc * a01.x + ba.x,  v1 = dc * a01.y + ba.y;
    float v2 = dc * a23.x + ba.z,  v3 = dc * a23.y + ba.w;
    float v4 = dc * a45.x + bb4.x, v5 = dc * a45.y + bb4.y;
    float v6 = dc * a67.x + bb4.z, v7 = dc * a67.y + bb4.w;
    v0 = v0 > 0.f ? v0 * dc : 0.f; v1 = v1 > 0.f ? v1 * dc : 0.f;
    v2 = v2 > 0.f ? v2 * dc : 0.f; v3 = v3 > 0.f ? v3 * dc : 0.f;
    v4 = v4 > 0.f ? v4 * dc : 0.f; v5 = v5 > 0.f ? v5 * dc : 0.f;
    v6 = v6 > 0.f ? v6 * dc : 0.f; v7 = v7 > 0.f ? v7 * dc : 0.f;
    __half hh[8];
    hh[0] = __float2half(v0); hh[1] = __float2half(v1);
    hh[2] = __float2half(v2); hh[3] = __float2half(v3);
    hh[4] = __float2half(v4); hh[5] = __float2half(v5);
    hh[6] = __float2half(v6); hh[7] = __float2half(v7);
    *(uint4*)(o1h + ((size_t)node * 64 + seg * 8)) = *(uint4*)hh;
}

// ---------------- layer-2 aggregation: 8 nodes/wave + per-group softmax/argmax ----------------
__global__ __launch_bounds__(256) void k_agg2(const int* __restrict__ off, const int* __restrict__ pdeg,
                                              const int* __restrict__ srow, const float* __restrict__ dinv,
                                              const unsigned char* __restrict__ h2q,
                                              const float* __restrict__ pb2, const int* __restrict__ y,
                                              float* __restrict__ out, unsigned short* __restrict__ ps) {
    int t = threadIdx.x;
    int lane = t & 63;
    int e = lane >> 3, seg = lane & 7;
    int node = ((blockIdx.x * 256 + t) >> 6) * 8 + e;
    int myoff = off[node];
    int mydeg = pdeg[node];
    GATHER_PL(h2q)
    float dc = dinv[node] * 0.125f;   // undo the x8 h2q scale
    float4 ba = *(const float4*)(pb2 + seg * 8);
    float4 bb4 = *(const float4*)(pb2 + seg * 8 + 4);
    bool act = seg < 5;               // classes seg*8..seg*8+7, 40 = 5*8
    float v0 = act ? (dc * a01.x + ba.x)  : -1e30f;
    float v1 = act ? (dc * a01.y + ba.y)  : -1e30f;
    float v2 = act ? (dc * a23.x + ba.z)  : -1e30f;
    float v3 = act ? (dc * a23.y + ba.w)  : -1e30f;
    float v4 = act ? (dc * a45.x + bb4.x) : -1e30f;
    float v5 = act ? (dc * a45.y + bb4.y) : -1e30f;
    float v6 = act ? (dc * a67.x + bb4.z) : -1e30f;
    float v7 = act ? (dc * a67.y + bb4.w) : -1e30f;
    // per-lane max + first-occurrence argmax over this lane's 8 classes
    float m = v0; int aj = 0;
    if (v1 > m) { m = v1; aj = 1; }
    if (v2 > m) { m = v2; aj = 2; }
    if (v3 > m) { m = v3; aj = 3; }
    if (v4 > m) { m = v4; aj = 4; }
    if (v5 > m) { m = v5; aj = 5; }
    if (v6 > m) { m = v6; aj = 6; }
    if (v7 > m) { m = v7; aj = 7; }
    int ac = seg * 8 + aj;
#pragma unroll
    for (int k = 1; k < 8; k <<= 1) {   // reduce within the 8-lane e-group
        float om = __shfl_xor(m, k);
        int oc = __shfl_xor(ac, k);
        if (om > m || (om == m && oc < ac)) { m = om; ac = oc; }
    }
    float s = 0.f;
    if (act) {
        s = expf(v0 - m) + expf(v1 - m) + expf(v2 - m) + expf(v3 - m)
          + expf(v4 - m) + expf(v5 - m) + expf(v6 - m) + expf(v7 - m);
    }
#pragma unroll
    for (int k = 1; k < 8; k <<= 1) s += __shfl_xor(s, k);
    float ls = logf(s);
    if (act) {
        float lp0 = (v0 - m) - ls, lp1 = (v1 - m) - ls, lp2 = (v2 - m) - ls, lp3 = (v3 - m) - ls;
        float lp4 = (v4 - m) - ls, lp5 = (v5 - m) - ls, lp6 = (v6 - m) - ls, lp7 = (v7 - m) - ls;
        float* logp = out + (size_t)node * N_CLASS + seg * 8;
        *(float4*)logp       = make_float4(lp0, lp1, lp2, lp3);
        *(float4*)(logp + 4) = make_float4(lp4, lp5, lp6, lp7);
        float* pp = out + (size_t)N_NODES * N_CLASS + (size_t)node * N_CLASS + seg * 8;
        *(float4*)pp       = make_float4(expf(lp0), expf(lp1), expf(lp2), expf(lp3));
        *(float4*)(pp + 4) = make_float4(expf(lp4), expf(lp5), expf(lp6), expf(lp7));
    }
    if (seg == 0) ps[node] = (unsigned short)((y[node] << 8) | ac);
}

// ---------------- ratio over original edges (8 edges / iter) ----------------
__global__ __launch_bounds__(256) void k_ratio(const int* __restrict__ row, const int* __restrict__ col,
                                               const unsigned short* __restrict__ ps,
                                               unsigned int* __restrict__ cnt) {
    int i = blockIdx.x * 256 + threadIdx.x;
    int stride = gridDim.x * 256;
    unsigned int local = 0;
    for (int e8 = i; e8 < N_EDGES / 8; e8 += stride) {
        int4 ra = ((const int4*)row)[e8 * 2];
        int4 rb = ((const int4*)row)[e8 * 2 + 1];
        int4 ca = ((const int4*)col)[e8 * 2];
        int4 cb = ((const int4*)col)[e8 * 2 + 1];
        unsigned int pa[8], pb[8];
        pa[0] = ps[ra.x]; pa[1] = ps[ra.y]; pa[2] = ps[ra.z]; pa[3] = ps[ra.w];
        pa[4] = ps[rb.x]; pa[5] = ps[rb.y]; pa[6] = ps[rb.z]; pa[7] = ps[rb.w];
        pb[0] = ps[ca.x]; pb[1] = ps[ca.y]; pb[2] = ps[ca.z]; pb[3] = ps[ca.w];
        pb[4] = ps[cb.x]; pb[5] = ps[cb.y]; pb[6] = ps[cb.z]; pb[7] = ps[cb.w];
#pragma unroll
        for (int k = 0; k < 8; ++k) {
            bool sp = (pa[k] & 0xffu) == (pb[k] & 0xffu);
            bool sy = (pa[k] >> 8) == (pb[k] >> 8);
            local += (sp == sy) ? 1u : 0u;
        }
    }
    if (local) atomicAdd(cnt, local);
}

__global__ void k_fin(const unsigned int* __restrict__ cnt, float* __restrict__ out) {
    out[0] = (float)(*cnt) / (float)N_EDGES;
}

extern "C" void kernel_launch(void* const* d_in, const int* in_sizes, int n_in,
                              void* d_out, int out_size, void* d_ws, size_t ws_size,
                              hipStream_t stream) {
    const float* x  = (const float*)d_in[0];
    const int*   ei = (const int*)d_in[1];
    const int*   y  = (const int*)d_in[2];
    const float* W1 = (const float*)d_in[3];
    const float* b1 = (const float*)d_in[4];
    const float* W2 = (const float*)d_in[5];
    const float* b2 = (const float*)d_in[6];

    const int* row = ei;
    const int* col = ei + N_EDGES;

    float* ws = (float*)d_ws;
    // workspace layout (4B units); fp8 tables have N_NODES+1 rows (sentinel)
    unsigned char* h1q = (unsigned char*)ws;               // (N+1)*64 B
    unsigned char* h2q = (unsigned char*)(ws + 1700000);   // (N+1)*64 B
    float* dinv   = ws + 3400000;                   // N
    int*   pdeg   = (int*)(ws + 3500000);           // N
    int*   off    = (int*)(ws + 3600000);           // N
    int*   srow   = (int*)(ws + 3700000);           // padded CSR (~4.0M) + tail slack
    int*   ghistT = (int*)(ws + 7800000);           // 256*512 (bucket-major)
    int*   goffT  = (int*)(ws + 8000000);           // 256*512
    int*   tot    = (int*)(ws + 8150000);           // 256
    int*   bbase  = (int*)(ws + 8200000);           // 256
    int*   bend   = (int*)(ws + 8201000);           // 256
    float* pb2    = ws + 8202000;                   // 64 (padded b2)
    unsigned short* ps = (unsigned short*)(ws + 8210000);  // N ushort
    unsigned int* cnt  = (unsigned int*)(ws + 8300000);
    unsigned int* epair = (unsigned int*)(ws + 8400000);   // E uint32 (ends ~11.6M)
    __half* o1h   = (__half*)(ws + 11700000);       // N*64 halves (12.8 MB)

    float* out = (float*)d_out;

    (void)hipMemsetAsync(cnt, 0, 4, stream);

    const int GEMM_GRID = (N_NODES + 127) / 128;
    const int AGG_GRID = N_NODES / 32;              // 8 nodes/wave * 4 waves = 32 nodes/block

    k_A1<<<NBLK_A, 256, 0, stream>>>(col, ghistT);
    k_A2a<<<256, 256, 0, stream>>>(ghistT, goffT, tot);
    k_A2b<<<1, 256, 0, stream>>>(tot, bbase, bend, h1q, h2q, b2, pb2);
    k_A3<<<NBLK_A, 256, 0, stream>>>(row, col, goffT, bbase, epair);
    k_B<<<NBUCK, 256, 0, stream>>>(epair, bbase, bend, off, pdeg, dinv, srow);
    k_gemm<F_IN, HID, 128><<<GEMM_GRID, 256, 0, stream>>>(x, W1, dinv, h1q);
    k_agg1<<<AGG_GRID, 256, 0, stream>>>(off, pdeg, srow, dinv, h1q, b1, o1h);
    k_gemm2<<<GEMM_GRID, 256, 0, stream>>>(o1h, W2, h2q);
    k_agg2<<<AGG_GRID, 256, 0, stream>>>(off, pdeg, srow, dinv, h2q, pb2, y, out, ps);
    k_ratio<<<2048, 256, 0, stream>>>(row, col, ps, cnt);
    k_fin<<<1, 1, 0, stream>>>(cnt, out + (size_t)2 * N_NODES * N_CLASS);
}

// Round 21
// 328.665 us; speedup vs baseline: 1.2744x; 1.1118x over previous
//
#include <hip/hip_runtime.h>
#include <hip/hip_fp16.h>

#define N_NODES 100000
#define N_EDGES 3200000
#define F_IN 128
#define HID 64
#define N_CLASS 40
#define ZROW N_NODES       // sentinel zero-row index

#define NBUCK 196          // ceil(100000/512)
#define BSHIFT 9
#define NBLK_A 512
#define CHUNK_A ((N_EDGES + NBLK_A - 1) / NBLK_A)

typedef float f32x2 __attribute__((ext_vector_type(2)));

static __device__ __forceinline__ unsigned char enc_fp8(float v) {
    return (unsigned char)(__builtin_amdgcn_cvt_pk_fp8_f32(v, v, 0, false) & 0xff);
}

// gather 8 fp8 bytes: byteoff = row<<6 (pre-shifted), seg in [0,8)
static __device__ __forceinline__ uint2 gat8(const unsigned char* base, int byteoff, int seg) {
    return *(const uint2*)(base + ((unsigned)byteoff | (unsigned)(seg << 3)));
}

// decode 8 fp8 (uint2), packed-f32 accumulate
#define CONS(RAW) do { \
    f32x2 f0 = __builtin_amdgcn_cvt_pk_f32_fp8((int)RAW.x, false); \
    f32x2 f1 = __builtin_amdgcn_cvt_pk_f32_fp8((int)RAW.x, true); \
    f32x2 f2 = __builtin_amdgcn_cvt_pk_f32_fp8((int)RAW.y, false); \
    f32x2 f3 = __builtin_amdgcn_cvt_pk_f32_fp8((int)RAW.y, true); \
    a01 += f0; a23 += f1; a45 += f2; a67 += f3; } while (0)

// per-lane pipelined slot: consume G (edge bb+s of MY node), issue edge bb+6+s,
// reload C with idx for edge bb+12+s (address clamped to my range)
#define SLOTP(s, G, C) { \
    int ib = bb + 6 + s; \
    int srcr = (ib < mydeg) ? C : zb; \
    uint2 ng = gat8(gsrc, srcr, seg); \
    C = sp[min(bb + 12 + s, mlast)]; \
    __builtin_amdgcn_sched_barrier(0); \
    CONS(G); \
    G = ng; }

// per-lane gather phase: each lane owns node `node` (e-group) and features seg*8..+7.
#define GATHER_PL(TBL) \
    f32x2 a01 = {0.f, 0.f}, a23 = {0.f, 0.f}, a45 = {0.f, 0.f}, a67 = {0.f, 0.f}; \
    { \
        const unsigned char* gsrc = TBL; \
        const int* sp = srow + myoff; \
        const int zb = ZROW << 6; \
        int nbmax = mydeg; \
        nbmax = max(nbmax, __shfl_xor(nbmax, 8)); \
        nbmax = max(nbmax, __shfl_xor(nbmax, 16)); \
        nbmax = max(nbmax, __shfl_xor(nbmax, 32)); \
        if (nbmax > 0) { \
            int mlast = mydeg > 0 ? mydeg - 1 : 0; \
            uint2 g0 = gat8(gsrc, (0 < mydeg) ? sp[0] : zb, seg); \
            uint2 g1 = gat8(gsrc, (1 < mydeg) ? sp[min(1, mlast)] : zb, seg); \
            uint2 g2 = gat8(gsrc, (2 < mydeg) ? sp[min(2, mlast)] : zb, seg); \
            uint2 g3 = gat8(gsrc, (3 < mydeg) ? sp[min(3, mlast)] : zb, seg); \
            uint2 g4 = gat8(gsrc, (4 < mydeg) ? sp[min(4, mlast)] : zb, seg); \
            uint2 g5 = gat8(gsrc, (5 < mydeg) ? sp[min(5, mlast)] : zb, seg); \
            int c0 = sp[min(6, mlast)],  c1 = sp[min(7, mlast)],  c2 = sp[min(8, mlast)]; \
            int c3 = sp[min(9, mlast)], c4 = sp[min(10, mlast)], c5 = sp[min(11, mlast)]; \
            for (int bb = 0; bb < nbmax; bb += 6) { \
                SLOTP(0, g0, c0) SLOTP(1, g1, c1) SLOTP(2, g2, c2) \
                SLOTP(3, g3, c3) SLOTP(4, g4, c4) SLOTP(5, g5, c5) \
            } \
        } \
        /* self term: every lane adds its own node's segment once */ \
        uint2 sg = gat8(gsrc, node << 6, seg); \
        CONS(sg); \
    }

// ---------------- Phase A1: per-block bucket histogram (transposed out) ----------------
__global__ __launch_bounds__(256) void k_A1(const int* __restrict__ col, int* __restrict__ ghistT) {
    __shared__ int hist[256];
    int t = threadIdx.x;
    hist[t] = 0;
    __syncthreads();
    int e0 = blockIdx.x * CHUNK_A;
    int e1 = e0 + CHUNK_A; if (e1 > N_EDGES) e1 = N_EDGES;
    for (int e = e0 + t; e < e1; e += 256) {
        atomicAdd(&hist[col[e] >> BSHIFT], 1);
    }
    __syncthreads();
    ghistT[t * NBLK_A + blockIdx.x] = hist[t];
}

// ---------------- Phase A2a: per-bucket scan over 512 A-blocks ----------------
__global__ __launch_bounds__(256) void k_A2a(const int* __restrict__ ghistT, int* __restrict__ goffT,
                                             int* __restrict__ tot) {
    __shared__ int s[256];
    int b = blockIdx.x, t = threadIdx.x;
    int2 v = ((const int2*)(ghistT + b * NBLK_A))[t];
    int pair = v.x + v.y;
    s[t] = pair;
    __syncthreads();
    for (int d = 1; d < 256; d <<= 1) {
        int o = (t >= d) ? s[t - d] : 0;
        __syncthreads();
        s[t] += o;
        __syncthreads();
    }
    int incl = s[t];
    int excl = incl - pair;
    goffT[b * NBLK_A + 2 * t]     = excl;
    goffT[b * NBLK_A + 2 * t + 1] = excl + v.x;
    if (t == 255) tot[b] = incl;
}

// ---------------- Phase A2b: scan of bucket totals + sentinel zero + padded b2 ----------------
__global__ __launch_bounds__(256) void k_A2b(const int* __restrict__ tot, int* __restrict__ bbase,
                                             int* __restrict__ bend,
                                             unsigned char* __restrict__ h1q,
                                             unsigned char* __restrict__ h2q,
                                             const float* __restrict__ b2, float* __restrict__ pb2) {
    __shared__ int s[256];
    int t = threadIdx.x;
    int v = tot[t];
    s[t] = v;
    __syncthreads();
    for (int d = 1; d < 256; d <<= 1) {
        int o = (t >= d) ? s[t - d] : 0;
        __syncthreads();
        s[t] += o;
        __syncthreads();
    }
    bbase[t] = s[t] - v;
    bend[t] = s[t];
    if (t < 64) h1q[(size_t)ZROW * 64 + t] = 0;
    else if (t < 128) h2q[(size_t)ZROW * 64 + (t - 64)] = 0;
    else if (t < 192) pb2[t - 128] = (t - 128 < N_CLASS) ? b2[t - 128] : 0.f;
}

// ---------------- Phase A3: coalesced-reserved bucket scatter ----------------
__global__ __launch_bounds__(256) void k_A3(const int* __restrict__ row, const int* __restrict__ col,
                                            const int* __restrict__ goffT, const int* __restrict__ bbase,
                                            unsigned int* __restrict__ epair) {
    __shared__ int cur[256];
    int t = threadIdx.x;
    cur[t] = goffT[t * NBLK_A + blockIdx.x] + bbase[t];
    __syncthreads();
    int e0 = blockIdx.x * CHUNK_A;
    int e1 = e0 + CHUNK_A; if (e1 > N_EDGES) e1 = N_EDGES;
    for (int e = e0 + t; e < e1; e += 256) {
        int c = col[e];
        int pos = atomicAdd(&cur[c >> BSHIFT], 1);
        epair[pos] = ((unsigned int)(c & 511) << 17) | (unsigned int)row[e];
    }
}

// ---------------- Phase B: per-bucket CSR build; srow holds (row<<6) byte offsets ----------------
__global__ __launch_bounds__(256) void k_B(const unsigned int* __restrict__ epair,
                                           const int* __restrict__ bbase, const int* __restrict__ bend,
                                           int* __restrict__ off, int* __restrict__ pdeg,
                                           float* __restrict__ dinv, int* __restrict__ srow) {
    __shared__ int h[512];
    __shared__ int psc[256];
    int t = threadIdx.x;
    int b = blockIdx.x;
    int n0 = b << BSHIFT;
    int e0 = bbase[b], e1 = bend[b];
    int pbase = e0 + b * 4096;
    h[t] = 0; h[t + 256] = 0;
    __syncthreads();
    for (int e = e0 + t; e < e1; e += 256) {
        atomicAdd(&h[epair[e] >> 17], 1);
    }
    __syncthreads();
    int a0 = h[2 * t], a1 = h[2 * t + 1];
    int p0 = (a0 + 7) & ~7, p1 = (a1 + 7) & ~7;
    psc[t] = p0 + p1;
    __syncthreads();
    for (int d = 1; d < 256; d <<= 1) {
        int o = (t >= d) ? psc[t - d] : 0;
        __syncthreads();
        psc[t] += o;
        __syncthreads();
    }
    int base0 = pbase + psc[t] - (p0 + p1);
    int base1 = base0 + p0;
    h[2 * t] = base0;
    h[2 * t + 1] = base1;
    int n = n0 + 2 * t;
    const int zb = ZROW << 6;
    if (n < N_NODES) {
        off[n] = base0; pdeg[n] = p0; dinv[n] = rsqrtf((float)a0 + 1.0f);
        for (int p = a0; p < p0; ++p) srow[base0 + p] = zb;
    }
    if (n + 1 < N_NODES) {
        off[n + 1] = base1; pdeg[n + 1] = p1; dinv[n + 1] = rsqrtf((float)a1 + 1.0f);
        for (int p = a1; p < p1; ++p) srow[base1 + p] = zb;
    }
    __syncthreads();
    for (int e = e0 + t; e < e1; e += 256) {
        unsigned int k = epair[e];
        int c = k >> 17;
        int pos = atomicAdd(&h[c], 1);
        srow[pos] = (int)(k & 0x1FFFFu) << 6;
    }
}

// ---------------- tiled dense GEMM (layer 1): h1q = fp8(dinv[n]*(X @ W1^T)) ----------------
template<int K, int C, int ROWS_PB>
__global__ __launch_bounds__(256, 4) void k_gemm(const float* __restrict__ X, const float* __restrict__ W,
                                                 const float* __restrict__ scale, unsigned char* __restrict__ O) {
    constexpr int PK = K + 4;
    __shared__ float ws[C * PK];
    __shared__ float xs[32 * PK];
    int t = threadIdx.x;
    for (int i4 = t; i4 < C * K / 4; i4 += 256) {
        int j = i4 / (K / 4);
        int k4 = i4 % (K / 4);
        float4 v = ((const float4*)W)[i4];
        *(float4*)&ws[j * PK + k4 * 4] = v;
    }
    int j = t & 63;
    int r0 = (t >> 6) * 8;
    int rowbase = blockIdx.x * ROWS_PB;
    for (int chunk = 0; chunk < ROWS_PB; chunk += 32) {
        int cb = rowbase + chunk;
        __syncthreads();
        for (int i4 = t; i4 < 32 * K / 4; i4 += 256) {
            int r = i4 / (K / 4);
            int k4 = i4 % (K / 4);
            int rr = cb + r;
            float4 v = make_float4(0.f, 0.f, 0.f, 0.f);
            if (rr < N_NODES) v = ((const float4*)X)[(size_t)rr * (K / 4) + k4];
            *(float4*)&xs[r * PK + k4 * 4] = v;
        }
        __syncthreads();
        if (j < C) {
            float acc[8] = {0.f, 0.f, 0.f, 0.f, 0.f, 0.f, 0.f, 0.f};
#pragma unroll 2
            for (int k4 = 0; k4 < K / 4; ++k4) {
                float4 wv = *(const float4*)&ws[j * PK + k4 * 4];
#pragma unroll
                for (int r = 0; r < 8; ++r) {
                    float4 xv = *(const float4*)&xs[(r0 + r) * PK + k4 * 4];
                    acc[r] += xv.x * wv.x + xv.y * wv.y + xv.z * wv.z + xv.w * wv.w;
                }
            }
#pragma unroll
            for (int r = 0; r < 8; ++r) {
                int rr = cb + r0 + r;
                if (rr < N_NODES) O[(size_t)rr * 64 + j] = enc_fp8(acc[r] * scale[rr]);
            }
        }
    }
}

// ---------------- layer-2 dense GEMM: h2q = fp8(8 * (o1h @ W2^T)), rows padded to 64 ----------------
__global__ __launch_bounds__(256, 4) void k_gemm2(const __half* __restrict__ o1h, const float* __restrict__ W2,
                                                  unsigned char* __restrict__ h2q) {
    __shared__ float ws2[N_CLASS * 68];
    __shared__ float xs[32 * 68];
    int t = threadIdx.x;
    for (int i = t; i < N_CLASS * HID; i += 256) {
        int c = i >> 6, k = i & 63;
        ws2[c * 68 + k] = W2[i] * 8.f;   // fold output scale
    }
    int j = t & 63;
    int cl = j < N_CLASS ? j : N_CLASS - 1;
    int r0 = (t >> 6) * 8;
    int rowbase = blockIdx.x * 128;
    for (int chunk = 0; chunk < 128; chunk += 32) {
        int cb = rowbase + chunk;
        __syncthreads();
        {
            int r = t >> 3, k8 = t & 7;
            int rr = cb + r;
            uint4 rawh = make_uint4(0u, 0u, 0u, 0u);
            if (rr < N_NODES) rawh = *(const uint4*)(o1h + (size_t)rr * 64 + k8 * 8);
            __half2* hp = (__half2*)&rawh;
            float2 f0 = __half22float2(hp[0]);
            float2 f1 = __half22float2(hp[1]);
            float2 f2 = __half22float2(hp[2]);
            float2 f3 = __half22float2(hp[3]);
            *(float4*)&xs[r * 68 + k8 * 8]     = make_float4(f0.x, f0.y, f1.x, f1.y);
            *(float4*)&xs[r * 68 + k8 * 8 + 4] = make_float4(f2.x, f2.y, f3.x, f3.y);
        }
        __syncthreads();
        float acc[8] = {0.f, 0.f, 0.f, 0.f, 0.f, 0.f, 0.f, 0.f};
#pragma unroll 2
        for (int k4 = 0; k4 < HID / 4; ++k4) {
            float4 wv = *(const float4*)&ws2[cl * 68 + k4 * 4];
#pragma unroll
            for (int r = 0; r < 8; ++r) {
                float4 xv = *(const float4*)&xs[(r0 + r) * 68 + k4 * 4];
                acc[r] += xv.x * wv.x + xv.y * wv.y + xv.z * wv.z + xv.w * wv.w;
            }
        }
#pragma unroll
        for (int r = 0; r < 8; ++r) {
            int rr = cb + r0 + r;
            if (rr < N_NODES) h2q[(size_t)rr * 64 + j] = (j < N_CLASS) ? enc_fp8(acc[r]) : (unsigned char)0;
        }
    }
}

// ---------------- layer-1 aggregation: 8 nodes/wave, per-lane accumulate, no reduce ----------------
__global__ __launch_bounds__(256) void k_agg1(const int* __restrict__ off, const int* __restrict__ pdeg,
                                              const int* __restrict__ srow, const float* __restrict__ dinv,
                                              const unsigned char* __restrict__ h1q, const float* __restrict__ b1,
                                              __half* __restrict__ o1h) {
    int t = threadIdx.x;
    int lane = t & 63;
    int e = lane >> 3, seg = lane & 7;
    int node = ((blockIdx.x * 256 + t) >> 6) * 8 + e;   // 8 consecutive nodes per wave
    int myoff = off[node];
    int mydeg = pdeg[node];
    GATHER_PL(h1q)
    float dc = dinv[node];
    float4 ba = *(const float4*)(b1 + seg * 8);
    float4 bb4 = *(const float4*)(b1 + seg * 8 + 4);
    float v0 = dc * a01.x + ba.x,  v1 = dc * a01.y + ba.y;
    float v2 = dc * a23.x + ba.z,  v3 = dc * a23.y + ba.w;
    float v4 = dc * a45.x + bb4.x, v5 = dc * a45.y + bb4.y;
    float v6 = dc * a67.x + bb4.z, v7 = dc * a67.y + bb4.w;
    v0 = v0 > 0.f ? v0 * dc : 0.f; v1 = v1 > 0.f ? v1 * dc : 0.f;
    v2 = v2 > 0.f ? v2 * dc : 0.f; v3 = v3 > 0.f ? v3 * dc : 0.f;
    v4 = v4 > 0.f ? v4 * dc : 0.f; v5 = v5 > 0.f ? v5 * dc : 0.f;
    v6 = v6 > 0.f ? v6 * dc : 0.f; v7 = v7 > 0.f ? v7 * dc : 0.f;
    __half hh[8];
    hh[0] = __float2half(v0); hh[1] = __float2half(v1);
    hh[2] = __float2half(v2); hh[3] = __float2half(v3);
    hh[4] = __float2half(v4); hh[5] = __float2half(v5);
    hh[6] = __float2half(v6); hh[7] = __float2half(v7);
    *(uint4*)(o1h + ((size_t)node * 64 + seg * 8)) = *(uint4*)hh;
}

// ---------------- layer-2 aggregation: 8 nodes/wave + per-group softmax/argmax ----------------
__global__ __launch_bounds__(256) void k_agg2(const int* __restrict__ off, const int* __restrict__ pdeg,
                                              const int* __restrict__ srow, const float* __restrict__ dinv,
                                              const unsigned char* __restrict__ h2q,
                                              const float* __restrict__ pb2, const int* __restrict__ y,
                                              float* __restrict__ out, unsigned short* __restrict__ ps) {
    int t = threadIdx.x;
    int lane = t & 63;
    int e = lane >> 3, seg = lane & 7;
    int node = ((blockIdx.x * 256 + t) >> 6) * 8 + e;
    int myoff = off[node];
    int mydeg = pdeg[node];
    GATHER_PL(h2q)
    float dc = dinv[node] * 0.125f;   // undo the x8 h2q scale
    float4 ba = *(const float4*)(pb2 + seg * 8);
    float4 bb4 = *(const float4*)(pb2 + seg * 8 + 4);
    bool act = seg < 5;               // classes seg*8..seg*8+7, 40 = 5*8
    float v0 = act ? (dc * a01.x + ba.x)  : -1e30f;
    float v1 = act ? (dc * a01.y + ba.y)  : -1e30f;
    float v2 = act ? (dc * a23.x + ba.z)  : -1e30f;
    float v3 = act ? (dc * a23.y + ba.w)  : -1e30f;
    float v4 = act ? (dc * a45.x + bb4.x) : -1e30f;
    float v5 = act ? (dc * a45.y + bb4.y) : -1e30f;
    float v6 = act ? (dc * a67.x + bb4.z) : -1e30f;
    float v7 = act ? (dc * a67.y + bb4.w) : -1e30f;
    // per-lane max + first-occurrence argmax over this lane's 8 classes
    float m = v0; int aj = 0;
    if (v1 > m) { m = v1; aj = 1; }
    if (v2 > m) { m = v2; aj = 2; }
    if (v3 > m) { m = v3; aj = 3; }
    if (v4 > m) { m = v4; aj = 4; }
    if (v5 > m) { m = v5; aj = 5; }
    if (v6 > m) { m = v6; aj = 6; }
    if (v7 > m) { m = v7; aj = 7; }
    int ac = seg * 8 + aj;
#pragma unroll
    for (int k = 1; k < 8; k <<= 1) {   // reduce within the 8-lane e-group
        float om = __shfl_xor(m, k);
        int oc = __shfl_xor(ac, k);
        if (om > m || (om == m && oc < ac)) { m = om; ac = oc; }
    }
    float s = 0.f;
    if (act) {
        s = expf(v0 - m) + expf(v1 - m) + expf(v2 - m) + expf(v3 - m)
          + expf(v4 - m) + expf(v5 - m) + expf(v6 - m) + expf(v7 - m);
    }
#pragma unroll
    for (int k = 1; k < 8; k <<= 1) s += __shfl_xor(s, k);
    float ls = logf(s);
    if (act) {
        float lp0 = (v0 - m) - ls, lp1 = (v1 - m) - ls, lp2 = (v2 - m) - ls, lp3 = (v3 - m) - ls;
        float lp4 = (v4 - m) - ls, lp5 = (v5 - m) - ls, lp6 = (v6 - m) - ls, lp7 = (v7 - m) - ls;
        float* logp = out + (size_t)node * N_CLASS + seg * 8;
        *(float4*)logp       = make_float4(lp0, lp1, lp2, lp3);
        *(float4*)(logp + 4) = make_float4(lp4, lp5, lp6, lp7);
        float* pp = out + (size_t)N_NODES * N_CLASS + (size_t)node * N_CLASS + seg * 8;
        *(float4*)pp       = make_float4(expf(lp0), expf(lp1), expf(lp2), expf(lp3));
        *(float4*)(pp + 4) = make_float4(expf(lp4), expf(lp5), expf(lp6), expf(lp7));
    }
    if (seg == 0) ps[node] = (unsigned short)((y[node] << 8) | ac);
}

// ---------------- ratio: software-pipelined, ~3 iterations/thread ----------------
#define RATIO_BLOCKS 512
__global__ __launch_bounds__(256) void k_ratio(const int* __restrict__ row, const int* __restrict__ col,
                                               const unsigned short* __restrict__ ps,
                                               unsigned int* __restrict__ cnt) {
    const int G = N_EDGES / 8;
    int i = blockIdx.x * 256 + threadIdx.x;
    int stride = RATIO_BLOCKS * 256;
    unsigned int local = 0;
    int e8 = i;
    if (e8 < G) {
        int4 ra = ((const int4*)row)[e8 * 2];
        int4 rb = ((const int4*)row)[e8 * 2 + 1];
        int4 ca = ((const int4*)col)[e8 * 2];
        int4 cb = ((const int4*)col)[e8 * 2 + 1];
        for (;;) {
            int en = e8 + stride;
            bool more = en < G;
            int4 nra, nrb, nca, ncb;
            if (more) {                      // issue next iteration's edge loads now
                nra = ((const int4*)row)[en * 2];
                nrb = ((const int4*)row)[en * 2 + 1];
                nca = ((const int4*)col)[en * 2];
                ncb = ((const int4*)col)[en * 2 + 1];
            }
            unsigned int pa[8], pb[8];       // 16 independent gathers in flight
            pa[0] = ps[ra.x]; pa[1] = ps[ra.y]; pa[2] = ps[ra.z]; pa[3] = ps[ra.w];
            pa[4] = ps[rb.x]; pa[5] = ps[rb.y]; pa[6] = ps[rb.z]; pa[7] = ps[rb.w];
            pb[0] = ps[ca.x]; pb[1] = ps[ca.y]; pb[2] = ps[ca.z]; pb[3] = ps[ca.w];
            pb[4] = ps[cb.x]; pb[5] = ps[cb.y]; pb[6] = ps[cb.z]; pb[7] = ps[cb.w];
#pragma unroll
            for (int k = 0; k < 8; ++k) {
                bool sp = (pa[k] & 0xffu) == (pb[k] & 0xffu);
                bool sy = (pa[k] >> 8) == (pb[k] >> 8);
                local += (sp == sy) ? 1u : 0u;
            }
            if (!more) break;
            ra = nra; rb = nrb; ca = nca; cb = ncb;
            e8 = en;
        }
    }
    if (local) atomicAdd(cnt, local);
}

__global__ void k_fin(const unsigned int* __restrict__ cnt, float* __restrict__ out) {
    out[0] = (float)(*cnt) / (float)N_EDGES;
}

extern "C" void kernel_launch(void* const* d_in, const int* in_sizes, int n_in,
                              void* d_out, int out_size, void* d_ws, size_t ws_size,
                              hipStream_t stream) {
    const float* x  = (const float*)d_in[0];
    const int*   ei = (const int*)d_in[1];
    const int*   y  = (const int*)d_in[2];
    const float* W1 = (const float*)d_in[3];
    const float* b1 = (const float*)d_in[4];
    const float* W2 = (const float*)d_in[5];
    const float* b2 = (const float*)d_in[6];

    const int* row = ei;
    const int* col = ei + N_EDGES;

    float* ws = (float*)d_ws;
    // workspace layout (4B units); fp8 tables have N_NODES+1 rows (sentinel)
    unsigned char* h1q = (unsigned char*)ws;               // (N+1)*64 B
    unsigned char* h2q = (unsigned char*)(ws + 1700000);   // (N+1)*64 B
    float* dinv   = ws + 3400000;                   // N
    int*   pdeg   = (int*)(ws + 3500000);           // N
    int*   off    = (int*)(ws + 3600000);           // N
    int*   srow   = (int*)(ws + 3700000);           // padded CSR (~4.0M) + tail slack
    int*   ghistT = (int*)(ws + 7800000);           // 256*512 (bucket-major)
    int*   goffT  = (int*)(ws + 8000000);           // 256*512
    int*   tot    = (int*)(ws + 8150000);           // 256
    int*   bbase  = (int*)(ws + 8200000);           // 256
    int*   bend   = (int*)(ws + 8201000);           // 256
    float* pb2    = ws + 8202000;                   // 64 (padded b2)
    unsigned short* ps = (unsigned short*)(ws + 8210000);  // N ushort
    unsigned int* cnt  = (unsigned int*)(ws + 8300000);
    unsigned int* epair = (unsigned int*)(ws + 8400000);   // E uint32 (ends ~11.6M)
    __half* o1h   = (__half*)(ws + 11700000);       // N*64 halves (12.8 MB)

    float* out = (float*)d_out;

    (void)hipMemsetAsync(cnt, 0, 4, stream);

    const int GEMM_GRID = (N_NODES + 127) / 128;
    const int AGG_GRID = N_NODES / 32;              // 8 nodes/wave * 4 waves = 32 nodes/block

    k_A1<<<NBLK_A, 256, 0, stream>>>(col, ghistT);
    k_A2a<<<256, 256, 0, stream>>>(ghistT, goffT, tot);
    k_A2b<<<1, 256, 0, stream>>>(tot, bbase, bend, h1q, h2q, b2, pb2);
    k_A3<<<NBLK_A, 256, 0, stream>>>(row, col, goffT, bbase, epair);
    k_B<<<NBUCK, 256, 0, stream>>>(epair, bbase, bend, off, pdeg, dinv, srow);
    k_gemm<F_IN, HID, 128><<<GEMM_GRID, 256, 0, stream>>>(x, W1, dinv, h1q);
    k_agg1<<<AGG_GRID, 256, 0, stream>>>(off, pdeg, srow, dinv, h1q, b1, o1h);
    k_gemm2<<<GEMM_GRID, 256, 0, stream>>>(o1h, W2, h2q);
    k_agg2<<<AGG_GRID, 256, 0, stream>>>(off, pdeg, srow, dinv, h2q, pb2, y, out, ps);
    k_ratio<<<RATIO_BLOCKS, 256, 0, stream>>>(row, col, ps, cnt);
    k_fin<<<1, 1, 0, stream>>>(cnt, out + (size_t)2 * N_NODES * N_CLASS);
}

// Round 22
// 309.203 us; speedup vs baseline: 1.3546x; 1.0629x over previous
//
#include <hip/hip_runtime.h>
#include <hip/hip_fp16.h>

#define N_NODES 100000
#define N_EDGES 3200000
#define F_IN 128
#define HID 64
#define N_CLASS 40
#define ZROW N_NODES       // sentinel zero-row index

#define NBUCK 196          // ceil(100000/512)
#define BSHIFT 9
#define NBLK_A 512
#define CHUNK_A ((N_EDGES + NBLK_A - 1) / NBLK_A)

typedef float f32x2 __attribute__((ext_vector_type(2)));

static __device__ __forceinline__ unsigned char enc_fp8(float v) {
    return (unsigned char)(__builtin_amdgcn_cvt_pk_fp8_f32(v, v, 0, false) & 0xff);
}

// gather 8 fp8 bytes: byteoff = row<<6 (pre-shifted), seg in [0,8)
static __device__ __forceinline__ uint2 gat8(const unsigned char* base, int byteoff, int seg) {
    return *(const uint2*)(base + ((unsigned)byteoff | (unsigned)(seg << 3)));
}

// decode 8 fp8 (uint2), packed-f32 accumulate
#define CONS(RAW) do { \
    f32x2 f0 = __builtin_amdgcn_cvt_pk_f32_fp8((int)RAW.x, false); \
    f32x2 f1 = __builtin_amdgcn_cvt_pk_f32_fp8((int)RAW.x, true); \
    f32x2 f2 = __builtin_amdgcn_cvt_pk_f32_fp8((int)RAW.y, false); \
    f32x2 f3 = __builtin_amdgcn_cvt_pk_f32_fp8((int)RAW.y, true); \
    a01 += f0; a23 += f1; a45 += f2; a67 += f3; } while (0)

// per-lane pipelined slot: consume G (edge bb+s of MY node), issue edge bb+6+s,
// reload C with idx for edge bb+12+s (address clamped to my range)
#define SLOTP(s, G, C) { \
    int ib = bb + 6 + s; \
    int srcr = (ib < mydeg) ? C : zb; \
    uint2 ng = gat8(gsrc, srcr, seg); \
    C = sp[min(bb + 12 + s, mlast)]; \
    __builtin_amdgcn_sched_barrier(0); \
    CONS(G); \
    G = ng; }

// per-lane gather phase: each lane owns node `node` (e-group) and features seg*8..+7.
#define GATHER_PL(TBL) \
    f32x2 a01 = {0.f, 0.f}, a23 = {0.f, 0.f}, a45 = {0.f, 0.f}, a67 = {0.f, 0.f}; \
    { \
        const unsigned char* gsrc = TBL; \
        const int* sp = srow + myoff; \
        const int zb = ZROW << 6; \
        int nbmax = mydeg; \
        nbmax = max(nbmax, __shfl_xor(nbmax, 8)); \
        nbmax = max(nbmax, __shfl_xor(nbmax, 16)); \
        nbmax = max(nbmax, __shfl_xor(nbmax, 32)); \
        if (nbmax > 0) { \
            int mlast = mydeg > 0 ? mydeg - 1 : 0; \
            uint2 g0 = gat8(gsrc, (0 < mydeg) ? sp[0] : zb, seg); \
            uint2 g1 = gat8(gsrc, (1 < mydeg) ? sp[min(1, mlast)] : zb, seg); \
            uint2 g2 = gat8(gsrc, (2 < mydeg) ? sp[min(2, mlast)] : zb, seg); \
            uint2 g3 = gat8(gsrc, (3 < mydeg) ? sp[min(3, mlast)] : zb, seg); \
            uint2 g4 = gat8(gsrc, (4 < mydeg) ? sp[min(4, mlast)] : zb, seg); \
            uint2 g5 = gat8(gsrc, (5 < mydeg) ? sp[min(5, mlast)] : zb, seg); \
            int c0 = sp[min(6, mlast)],  c1 = sp[min(7, mlast)],  c2 = sp[min(8, mlast)]; \
            int c3 = sp[min(9, mlast)], c4 = sp[min(10, mlast)], c5 = sp[min(11, mlast)]; \
            for (int bb = 0; bb < nbmax; bb += 6) { \
                SLOTP(0, g0, c0) SLOTP(1, g1, c1) SLOTP(2, g2, c2) \
                SLOTP(3, g3, c3) SLOTP(4, g4, c4) SLOTP(5, g5, c5) \
            } \
        } \
        /* self term: every lane adds its own node's segment once */ \
        uint2 sg = gat8(gsrc, node << 6, seg); \
        CONS(sg); \
    }

// ---------------- Phase A1: per-block bucket histogram (transposed out) ----------------
__global__ __launch_bounds__(256) void k_A1(const int* __restrict__ col, int* __restrict__ ghistT) {
    __shared__ int hist[256];
    int t = threadIdx.x;
    hist[t] = 0;
    __syncthreads();
    int e0 = blockIdx.x * CHUNK_A;
    int e1 = e0 + CHUNK_A; if (e1 > N_EDGES) e1 = N_EDGES;
    for (int e = e0 + t; e < e1; e += 256) {
        atomicAdd(&hist[col[e] >> BSHIFT], 1);
    }
    __syncthreads();
    ghistT[t * NBLK_A + blockIdx.x] = hist[t];
}

// ---------------- Phase A2a: per-bucket scan over 512 A-blocks ----------------
__global__ __launch_bounds__(256) void k_A2a(const int* __restrict__ ghistT, int* __restrict__ goffT,
                                             int* __restrict__ tot) {
    __shared__ int s[256];
    int b = blockIdx.x, t = threadIdx.x;
    int2 v = ((const int2*)(ghistT + b * NBLK_A))[t];
    int pair = v.x + v.y;
    s[t] = pair;
    __syncthreads();
    for (int d = 1; d < 256; d <<= 1) {
        int o = (t >= d) ? s[t - d] : 0;
        __syncthreads();
        s[t] += o;
        __syncthreads();
    }
    int incl = s[t];
    int excl = incl - pair;
    goffT[b * NBLK_A + 2 * t]     = excl;
    goffT[b * NBLK_A + 2 * t + 1] = excl + v.x;
    if (t == 255) tot[b] = incl;
}

// ---------------- Phase A2b: scan of bucket totals + sentinel zero + padded b2 ----------------
__global__ __launch_bounds__(256) void k_A2b(const int* __restrict__ tot, int* __restrict__ bbase,
                                             int* __restrict__ bend,
                                             unsigned char* __restrict__ h1q,
                                             unsigned char* __restrict__ h2q,
                                             const float* __restrict__ b2, float* __restrict__ pb2) {
    __shared__ int s[256];
    int t = threadIdx.x;
    int v = tot[t];
    s[t] = v;
    __syncthreads();
    for (int d = 1; d < 256; d <<= 1) {
        int o = (t >= d) ? s[t - d] : 0;
        __syncthreads();
        s[t] += o;
        __syncthreads();
    }
    bbase[t] = s[t] - v;
    bend[t] = s[t];
    if (t < 64) h1q[(size_t)ZROW * 64 + t] = 0;
    else if (t < 128) h2q[(size_t)ZROW * 64 + (t - 64)] = 0;
    else if (t < 192) pb2[t - 128] = (t - 128 < N_CLASS) ? b2[t - 128] : 0.f;
}

// ---------------- Phase A3: coalesced-reserved bucket scatter ----------------
__global__ __launch_bounds__(256) void k_A3(const int* __restrict__ row, const int* __restrict__ col,
                                            const int* __restrict__ goffT, const int* __restrict__ bbase,
                                            unsigned int* __restrict__ epair) {
    __shared__ int cur[256];
    int t = threadIdx.x;
    cur[t] = goffT[t * NBLK_A + blockIdx.x] + bbase[t];
    __syncthreads();
    int e0 = blockIdx.x * CHUNK_A;
    int e1 = e0 + CHUNK_A; if (e1 > N_EDGES) e1 = N_EDGES;
    for (int e = e0 + t; e < e1; e += 256) {
        int c = col[e];
        int pos = atomicAdd(&cur[c >> BSHIFT], 1);
        epair[pos] = ((unsigned int)(c & 511) << 17) | (unsigned int)row[e];
    }
}

// ---------------- Phase B: per-bucket CSR build; srow holds (row<<6) byte offsets ----------------
__global__ __launch_bounds__(256) void k_B(const unsigned int* __restrict__ epair,
                                           const int* __restrict__ bbase, const int* __restrict__ bend,
                                           int* __restrict__ off, int* __restrict__ pdeg,
                                           float* __restrict__ dinv, int* __restrict__ srow) {
    __shared__ int h[512];
    __shared__ int psc[256];
    int t = threadIdx.x;
    int b = blockIdx.x;
    int n0 = b << BSHIFT;
    int e0 = bbase[b], e1 = bend[b];
    int pbase = e0 + b * 4096;
    h[t] = 0; h[t + 256] = 0;
    __syncthreads();
    for (int e = e0 + t; e < e1; e += 256) {
        atomicAdd(&h[epair[e] >> 17], 1);
    }
    __syncthreads();
    int a0 = h[2 * t], a1 = h[2 * t + 1];
    int p0 = (a0 + 7) & ~7, p1 = (a1 + 7) & ~7;
    psc[t] = p0 + p1;
    __syncthreads();
    for (int d = 1; d < 256; d <<= 1) {
        int o = (t >= d) ? psc[t - d] : 0;
        __syncthreads();
        psc[t] += o;
        __syncthreads();
    }
    int base0 = pbase + psc[t] - (p0 + p1);
    int base1 = base0 + p0;
    h[2 * t] = base0;
    h[2 * t + 1] = base1;
    int n = n0 + 2 * t;
    const int zb = ZROW << 6;
    if (n < N_NODES) {
        off[n] = base0; pdeg[n] = p0; dinv[n] = rsqrtf((float)a0 + 1.0f);
        for (int p = a0; p < p0; ++p) srow[base0 + p] = zb;
    }
    if (n + 1 < N_NODES) {
        off[n + 1] = base1; pdeg[n + 1] = p1; dinv[n + 1] = rsqrtf((float)a1 + 1.0f);
        for (int p = a1; p < p1; ++p) srow[base1 + p] = zb;
    }
    __syncthreads();
    for (int e = e0 + t; e < e1; e += 256) {
        unsigned int k = epair[e];
        int c = k >> 17;
        int pos = atomicAdd(&h[c], 1);
        srow[pos] = (int)(k & 0x1FFFFu) << 6;
    }
}

// ---------------- layer-1 GEMM: K-chunked, 64 rows/block -> 1563 blocks ----------------
// h1q = fp8(dinv[n] * (X @ W1^T)); LDS 26.1 KB (wsc 64x68 + xsc 32x68)
__global__ __launch_bounds__(256, 4) void k_gemm1(const float* __restrict__ X, const float* __restrict__ W,
                                                  const float* __restrict__ scale, unsigned char* __restrict__ O) {
    __shared__ float wsc[64 * 68];   // W chunk [j][kk], 17408 B
    __shared__ float xsc[32 * 68];   // x chunk [r][kk], 8704 B
    int t = threadIdx.x;
    int j = t & 63;
    int r0 = (t >> 6) * 8;
    int rowbase = blockIdx.x * 64;
    float acc[2][8] = {};
#pragma unroll
    for (int kc = 0; kc < 2; ++kc) {
        __syncthreads();   // previous readers of wsc done
        for (int i4 = t; i4 < 64 * 16; i4 += 256) {
            int jj = i4 >> 4, k4 = i4 & 15;
            float4 v = ((const float4*)W)[jj * 32 + kc * 16 + k4];
            *(float4*)&wsc[jj * 68 + k4 * 4] = v;
        }
#pragma unroll
        for (int chunk = 0; chunk < 2; ++chunk) {
            int cb = rowbase + chunk * 32;
            __syncthreads();   // wsc ready / xsc free
            for (int i4 = t; i4 < 32 * 16; i4 += 256) {
                int r = i4 >> 4, k4 = i4 & 15;
                int rr = cb + r;
                float4 v = make_float4(0.f, 0.f, 0.f, 0.f);
                if (rr < N_NODES) v = ((const float4*)X)[(size_t)rr * 32 + kc * 16 + k4];
                *(float4*)&xsc[r * 68 + k4 * 4] = v;
            }
            __syncthreads();
#pragma unroll 2
            for (int k4 = 0; k4 < 16; ++k4) {
                float4 wv = *(const float4*)&wsc[j * 68 + k4 * 4];
#pragma unroll
                for (int r = 0; r < 8; ++r) {
                    float4 xv = *(const float4*)&xsc[(r0 + r) * 68 + k4 * 4];
                    acc[chunk][r] += xv.x * wv.x + xv.y * wv.y + xv.z * wv.z + xv.w * wv.w;
                }
            }
        }
    }
#pragma unroll
    for (int chunk = 0; chunk < 2; ++chunk) {
#pragma unroll
        for (int r = 0; r < 8; ++r) {
            int rr = rowbase + chunk * 32 + r0 + r;
            if (rr < N_NODES) O[(size_t)rr * 64 + j] = enc_fp8(acc[chunk][r] * scale[rr]);
        }
    }
}

// ---------------- layer-2 dense GEMM: h2q = fp8(8 * (o1h @ W2^T)), 64 rows/block ----------------
__global__ __launch_bounds__(256, 4) void k_gemm2(const __half* __restrict__ o1h, const float* __restrict__ W2,
                                                  unsigned char* __restrict__ h2q) {
    __shared__ float ws2[N_CLASS * 68];
    __shared__ float xs[32 * 68];
    int t = threadIdx.x;
    for (int i = t; i < N_CLASS * HID; i += 256) {
        int c = i >> 6, k = i & 63;
        ws2[c * 68 + k] = W2[i] * 8.f;   // fold output scale
    }
    int j = t & 63;
    int cl = j < N_CLASS ? j : N_CLASS - 1;
    int r0 = (t >> 6) * 8;
    int rowbase = blockIdx.x * 64;
#pragma unroll
    for (int chunk = 0; chunk < 2; ++chunk) {
        int cb = rowbase + chunk * 32;
        __syncthreads();
        {
            int r = t >> 3, k8 = t & 7;
            int rr = cb + r;
            uint4 rawh = make_uint4(0u, 0u, 0u, 0u);
            if (rr < N_NODES) rawh = *(const uint4*)(o1h + (size_t)rr * 64 + k8 * 8);
            __half2* hp = (__half2*)&rawh;
            float2 f0 = __half22float2(hp[0]);
            float2 f1 = __half22float2(hp[1]);
            float2 f2 = __half22float2(hp[2]);
            float2 f3 = __half22float2(hp[3]);
            *(float4*)&xs[r * 68 + k8 * 8]     = make_float4(f0.x, f0.y, f1.x, f1.y);
            *(float4*)&xs[r * 68 + k8 * 8 + 4] = make_float4(f2.x, f2.y, f3.x, f3.y);
        }
        __syncthreads();
        float acc[8] = {0.f, 0.f, 0.f, 0.f, 0.f, 0.f, 0.f, 0.f};
#pragma unroll 2
        for (int k4 = 0; k4 < HID / 4; ++k4) {
            float4 wv = *(const float4*)&ws2[cl * 68 + k4 * 4];
#pragma unroll
            for (int r = 0; r < 8; ++r) {
                float4 xv = *(const float4*)&xs[(r0 + r) * 68 + k4 * 4];
                acc[r] += xv.x * wv.x + xv.y * wv.y + xv.z * wv.z + xv.w * wv.w;
            }
        }
#pragma unroll
        for (int r = 0; r < 8; ++r) {
            int rr = cb + r0 + r;
            if (rr < N_NODES) h2q[(size_t)rr * 64 + j] = (j < N_CLASS) ? enc_fp8(acc[r]) : (unsigned char)0;
        }
    }
}

// ---------------- layer-1 aggregation: 8 nodes/wave, per-lane accumulate, no reduce ----------------
__global__ __launch_bounds__(256) void k_agg1(const int* __restrict__ off, const int* __restrict__ pdeg,
                                              const int* __restrict__ srow, const float* __restrict__ dinv,
                                              const unsigned char* __restrict__ h1q, const float* __restrict__ b1,
                                              __half* __restrict__ o1h) {
    int t = threadIdx.x;
    int lane = t & 63;
    int e = lane >> 3, seg = lane & 7;
    int node = ((blockIdx.x * 256 + t) >> 6) * 8 + e;   // 8 consecutive nodes per wave
    int myoff = off[node];
    int mydeg = pdeg[node];
    GATHER_PL(h1q)
    float dc = dinv[node];
    float4 ba = *(const float4*)(b1 + seg * 8);
    float4 bb4 = *(const float4*)(b1 + seg * 8 + 4);
    float v0 = dc * a01.x + ba.x,  v1 = dc * a01.y + ba.y;
    float v2 = dc * a23.x + ba.z,  v3 = dc * a23.y + ba.w;
    float v4 = dc * a45.x + bb4.x, v5 = dc * a45.y + bb4.y;
    float v6 = dc * a67.x + bb4.z, v7 = dc * a67.y + bb4.w;
    v0 = v0 > 0.f ? v0 * dc : 0.f; v1 = v1 > 0.f ? v1 * dc : 0.f;
    v2 = v2 > 0.f ? v2 * dc : 0.f; v3 = v3 > 0.f ? v3 * dc : 0.f;
    v4 = v4 > 0.f ? v4 * dc : 0.f; v5 = v5 > 0.f ? v5 * dc : 0.f;
    v6 = v6 > 0.f ? v6 * dc : 0.f; v7 = v7 > 0.f ? v7 * dc : 0.f;
    __half hh[8];
    hh[0] = __float2half(v0); hh[1] = __float2half(v1);
    hh[2] = __float2half(v2); hh[3] = __float2half(v3);
    hh[4] = __float2half(v4); hh[5] = __float2half(v5);
    hh[6] = __float2half(v6); hh[7] = __float2half(v7);
    *(uint4*)(o1h + ((size_t)node * 64 + seg * 8)) = *(uint4*)hh;
}

// ---------------- layer-2 aggregation: 8 nodes/wave + per-group softmax/argmax ----------------
__global__ __launch_bounds__(256) void k_agg2(const int* __restrict__ off, const int* __restrict__ pdeg,
                                              const int* __restrict__ srow, const float* __restrict__ dinv,
                                              const unsigned char* __restrict__ h2q,
                                              const float* __restrict__ pb2, const int* __restrict__ y,
                                              float* __restrict__ out, unsigned short* __restrict__ ps) {
    int t = threadIdx.x;
    int lane = t & 63;
    int e = lane >> 3, seg = lane & 7;
    int node = ((blockIdx.x * 256 + t) >> 6) * 8 + e;
    int myoff = off[node];
    int mydeg = pdeg[node];
    GATHER_PL(h2q)
    float dc = dinv[node] * 0.125f;   // undo the x8 h2q scale
    float4 ba = *(const float4*)(pb2 + seg * 8);
    float4 bb4 = *(const float4*)(pb2 + seg * 8 + 4);
    bool act = seg < 5;               // classes seg*8..seg*8+7, 40 = 5*8
    float v0 = act ? (dc * a01.x + ba.x)  : -1e30f;
    float v1 = act ? (dc * a01.y + ba.y)  : -1e30f;
    float v2 = act ? (dc * a23.x + ba.z)  : -1e30f;
    float v3 = act ? (dc * a23.y + ba.w)  : -1e30f;
    float v4 = act ? (dc * a45.x + bb4.x) : -1e30f;
    float v5 = act ? (dc * a45.y + bb4.y) : -1e30f;
    float v6 = act ? (dc * a67.x + bb4.z) : -1e30f;
    float v7 = act ? (dc * a67.y + bb4.w) : -1e30f;
    // per-lane max + first-occurrence argmax over this lane's 8 classes
    float m = v0; int aj = 0;
    if (v1 > m) { m = v1; aj = 1; }
    if (v2 > m) { m = v2; aj = 2; }
    if (v3 > m) { m = v3; aj = 3; }
    if (v4 > m) { m = v4; aj = 4; }
    if (v5 > m) { m = v5; aj = 5; }
    if (v6 > m) { m = v6; aj = 6; }
    if (v7 > m) { m = v7; aj = 7; }
    int ac = seg * 8 + aj;
#pragma unroll
    for (int k = 1; k < 8; k <<= 1) {   // reduce within the 8-lane e-group
        float om = __shfl_xor(m, k);
        int oc = __shfl_xor(ac, k);
        if (om > m || (om == m && oc < ac)) { m = om; ac = oc; }
    }
    float s = 0.f;
    if (act) {
        s = expf(v0 - m) + expf(v1 - m) + expf(v2 - m) + expf(v3 - m)
          + expf(v4 - m) + expf(v5 - m) + expf(v6 - m) + expf(v7 - m);
    }
#pragma unroll
    for (int k = 1; k < 8; k <<= 1) s += __shfl_xor(s, k);
    float ls = logf(s);
    if (act) {
        float lp0 = (v0 - m) - ls, lp1 = (v1 - m) - ls, lp2 = (v2 - m) - ls, lp3 = (v3 - m) - ls;
        float lp4 = (v4 - m) - ls, lp5 = (v5 - m) - ls, lp6 = (v6 - m) - ls, lp7 = (v7 - m) - ls;
        float* logp = out + (size_t)node * N_CLASS + seg * 8;
        *(float4*)logp       = make_float4(lp0, lp1, lp2, lp3);
        *(float4*)(logp + 4) = make_float4(lp4, lp5, lp6, lp7);
        float* pp = out + (size_t)N_NODES * N_CLASS + (size_t)node * N_CLASS + seg * 8;
        *(float4*)pp       = make_float4(expf(lp0), expf(lp1), expf(lp2), expf(lp3));
        *(float4*)(pp + 4) = make_float4(expf(lp4), expf(lp5), expf(lp6), expf(lp7));
    }
    if (seg == 0) ps[node] = (unsigned short)((y[node] << 8) | ac);
}

// ---------------- ratio: software-pipelined, ~3 iterations/thread ----------------
#define RATIO_BLOCKS 512
__global__ __launch_bounds__(256) void k_ratio(const int* __restrict__ row, const int* __restrict__ col,
                                               const unsigned short* __restrict__ ps,
                                               unsigned int* __restrict__ cnt) {
    const int G = N_EDGES / 8;
    int i = blockIdx.x * 256 + threadIdx.x;
    int stride = RATIO_BLOCKS * 256;
    unsigned int local = 0;
    int e8 = i;
    if (e8 < G) {
        int4 ra = ((const int4*)row)[e8 * 2];
        int4 rb = ((const int4*)row)[e8 * 2 + 1];
        int4 ca = ((const int4*)col)[e8 * 2];
        int4 cb = ((const int4*)col)[e8 * 2 + 1];
        for (;;) {
            int en = e8 + stride;
            bool more = en < G;
            int4 nra, nrb, nca, ncb;
            if (more) {                      // issue next iteration's edge loads now
                nra = ((const int4*)row)[en * 2];
                nrb = ((const int4*)row)[en * 2 + 1];
                nca = ((const int4*)col)[en * 2];
                ncb = ((const int4*)col)[en * 2 + 1];
            }
            unsigned int pa[8], pb[8];       // 16 independent gathers in flight
            pa[0] = ps[ra.x]; pa[1] = ps[ra.y]; pa[2] = ps[ra.z]; pa[3] = ps[ra.w];
            pa[4] = ps[rb.x]; pa[5] = ps[rb.y]; pa[6] = ps[rb.z]; pa[7] = ps[rb.w];
            pb[0] = ps[ca.x]; pb[1] = ps[ca.y]; pb[2] = ps[ca.z]; pb[3] = ps[ca.w];
            pb[4] = ps[cb.x]; pb[5] = ps[cb.y]; pb[6] = ps[cb.z]; pb[7] = ps[cb.w];
#pragma unroll
            for (int k = 0; k < 8; ++k) {
                bool sp = (pa[k] & 0xffu) == (pb[k] & 0xffu);
                bool sy = (pa[k] >> 8) == (pb[k] >> 8);
                local += (sp == sy) ? 1u : 0u;
            }
            if (!more) break;
            ra = nra; rb = nrb; ca = nca; cb = ncb;
            e8 = en;
        }
    }
    if (local) atomicAdd(cnt, local);
}

__global__ void k_fin(const unsigned int* __restrict__ cnt, float* __restrict__ out) {
    out[0] = (float)(*cnt) / (float)N_EDGES;
}

extern "C" void kernel_launch(void* const* d_in, const int* in_sizes, int n_in,
                              void* d_out, int out_size, void* d_ws, size_t ws_size,
                              hipStream_t stream) {
    const float* x  = (const float*)d_in[0];
    const int*   ei = (const int*)d_in[1];
    const int*   y  = (const int*)d_in[2];
    const float* W1 = (const float*)d_in[3];
    const float* b1 = (const float*)d_in[4];
    const float* W2 = (const float*)d_in[5];
    const float* b2 = (const float*)d_in[6];

    const int* row = ei;
    const int* col = ei + N_EDGES;

    float* ws = (float*)d_ws;
    // workspace layout (4B units); fp8 tables have N_NODES+1 rows (sentinel)
    unsigned char* h1q = (unsigned char*)ws;               // (N+1)*64 B
    unsigned char* h2q = (unsigned char*)(ws + 1700000);   // (N+1)*64 B
    float* dinv   = ws + 3400000;                   // N
    int*   pdeg   = (int*)(ws + 3500000);           // N
    int*   off    = (int*)(ws + 3600000);           // N
    int*   srow   = (int*)(ws + 3700000);           // padded CSR (~4.0M) + tail slack
    int*   ghistT = (int*)(ws + 7800000);           // 256*512 (bucket-major)
    int*   goffT  = (int*)(ws + 8000000);           // 256*512
    int*   tot    = (int*)(ws + 8150000);           // 256
    int*   bbase  = (int*)(ws + 8200000);           // 256
    int*   bend   = (int*)(ws + 8201000);           // 256
    float* pb2    = ws + 8202000;                   // 64 (padded b2)
    unsigned short* ps = (unsigned short*)(ws + 8210000);  // N ushort
    unsigned int* cnt  = (unsigned int*)(ws + 8300000);
    unsigned int* epair = (unsigned int*)(ws + 8400000);   // E uint32 (ends ~11.6M)
    __half* o1h   = (__half*)(ws + 11700000);       // N*64 halves (12.8 MB)

    float* out = (float*)d_out;

    (void)hipMemsetAsync(cnt, 0, 4, stream);

    const int GEMM_GRID = (N_NODES + 63) / 64;      // 1563 blocks, 64 rows each
    const int AGG_GRID = N_NODES / 32;              // 8 nodes/wave * 4 waves = 32 nodes/block

    k_A1<<<NBLK_A, 256, 0, stream>>>(col, ghistT);
    k_A2a<<<256, 256, 0, stream>>>(ghistT, goffT, tot);
    k_A2b<<<1, 256, 0, stream>>>(tot, bbase, bend, h1q, h2q, b2, pb2);
    k_A3<<<NBLK_A, 256, 0, stream>>>(row, col, goffT, bbase, epair);
    k_B<<<NBUCK, 256, 0, stream>>>(epair, bbase, bend, off, pdeg, dinv, srow);
    k_gemm1<<<GEMM_GRID, 256, 0, stream>>>(x, W1, dinv, h1q);
    k_agg1<<<AGG_GRID, 256, 0, stream>>>(off, pdeg, srow, dinv, h1q, b1, o1h);
    k_gemm2<<<GEMM_GRID, 256, 0, stream>>>(o1h, W2, h2q);
    k_agg2<<<AGG_GRID, 256, 0, stream>>>(off, pdeg, srow, dinv, h2q, pb2, y, out, ps);
    k_ratio<<<RATIO_BLOCKS, 256, 0, stream>>>(row, col, ps, cnt);
    k_fin<<<1, 1, 0, stream>>>(cnt, out + (size_t)2 * N_NODES * N_CLASS);
}

// Round 23
// 278.397 us; speedup vs baseline: 1.5045x; 1.1107x over previous
//
#include <hip/hip_runtime.h>

#define N_NODES 100000
#define N_EDGES 3200000
#define F_IN 128
#define HID 64
#define N_CLASS 40
#define ZROW N_NODES       // sentinel zero-row index

#define NBUCK 196          // ceil(100000/512)
#define BSHIFT 9
#define NBLK_A 512
#define CHUNK_A ((N_EDGES + NBLK_A - 1) / NBLK_A)

typedef float f32x2 __attribute__((ext_vector_type(2)));
typedef __attribute__((ext_vector_type(8))) short bf16x8;
typedef __attribute__((ext_vector_type(4))) float f32x4v;

static __device__ __forceinline__ unsigned char enc_fp8(float v) {
    return (unsigned char)(__builtin_amdgcn_cvt_pk_fp8_f32(v, v, 0, false) & 0xff);
}
static __device__ __forceinline__ unsigned cvtpk_bf16(float lo, float hi) {
    unsigned r;
    asm("v_cvt_pk_bf16_f32 %0, %1, %2" : "=v"(r) : "v"(lo), "v"(hi));
    return r;
}

// gather 8 fp8 bytes: byteoff = row<<6 (pre-shifted), seg in [0,8)
static __device__ __forceinline__ uint2 gat8(const unsigned char* base, int byteoff, int seg) {
    return *(const uint2*)(base + ((unsigned)byteoff | (unsigned)(seg << 3)));
}

// decode 8 fp8 (uint2), packed-f32 accumulate
#define CONS(RAW) do { \
    f32x2 f0 = __builtin_amdgcn_cvt_pk_f32_fp8((int)RAW.x, false); \
    f32x2 f1 = __builtin_amdgcn_cvt_pk_f32_fp8((int)RAW.x, true); \
    f32x2 f2 = __builtin_amdgcn_cvt_pk_f32_fp8((int)RAW.y, false); \
    f32x2 f3 = __builtin_amdgcn_cvt_pk_f32_fp8((int)RAW.y, true); \
    a01 += f0; a23 += f1; a45 += f2; a67 += f3; } while (0)

// per-lane pipelined slot: consume G (edge bb+s of MY node), issue edge bb+6+s,
// reload C with idx for edge bb+12+s (address clamped to my range)
#define SLOTP(s, G, C) { \
    int ib = bb + 6 + s; \
    int srcr = (ib < mydeg) ? C : zb; \
    uint2 ng = gat8(gsrc, srcr, seg); \
    C = sp[min(bb + 12 + s, mlast)]; \
    __builtin_amdgcn_sched_barrier(0); \
    CONS(G); \
    G = ng; }

// per-lane gather phase: each lane owns node `node` (e-group) and features seg*8..+7.
#define GATHER_PL(TBL) \
    f32x2 a01 = {0.f, 0.f}, a23 = {0.f, 0.f}, a45 = {0.f, 0.f}, a67 = {0.f, 0.f}; \
    { \
        const unsigned char* gsrc = TBL; \
        const int* sp = srow + myoff; \
        const int zb = ZROW << 6; \
        int nbmax = mydeg; \
        nbmax = max(nbmax, __shfl_xor(nbmax, 8)); \
        nbmax = max(nbmax, __shfl_xor(nbmax, 16)); \
        nbmax = max(nbmax, __shfl_xor(nbmax, 32)); \
        if (nbmax > 0) { \
            int mlast = mydeg > 0 ? mydeg - 1 : 0; \
            uint2 g0 = gat8(gsrc, (0 < mydeg) ? sp[0] : zb, seg); \
            uint2 g1 = gat8(gsrc, (1 < mydeg) ? sp[min(1, mlast)] : zb, seg); \
            uint2 g2 = gat8(gsrc, (2 < mydeg) ? sp[min(2, mlast)] : zb, seg); \
            uint2 g3 = gat8(gsrc, (3 < mydeg) ? sp[min(3, mlast)] : zb, seg); \
            uint2 g4 = gat8(gsrc, (4 < mydeg) ? sp[min(4, mlast)] : zb, seg); \
            uint2 g5 = gat8(gsrc, (5 < mydeg) ? sp[min(5, mlast)] : zb, seg); \
            int c0 = sp[min(6, mlast)],  c1 = sp[min(7, mlast)],  c2 = sp[min(8, mlast)]; \
            int c3 = sp[min(9, mlast)], c4 = sp[min(10, mlast)], c5 = sp[min(11, mlast)]; \
            for (int bb = 0; bb < nbmax; bb += 6) { \
                SLOTP(0, g0, c0) SLOTP(1, g1, c1) SLOTP(2, g2, c2) \
                SLOTP(3, g3, c3) SLOTP(4, g4, c4) SLOTP(5, g5, c5) \
            } \
        } \
        /* self term: every lane adds its own node's segment once */ \
        uint2 sg = gat8(gsrc, node << 6, seg); \
        CONS(sg); \
    }

// ---------------- Phase A1: per-block bucket histogram (transposed out) ----------------
__global__ __launch_bounds__(256) void k_A1(const int* __restrict__ col, int* __restrict__ ghistT) {
    __shared__ int hist[256];
    int t = threadIdx.x;
    hist[t] = 0;
    __syncthreads();
    int e0 = blockIdx.x * CHUNK_A;
    int e1 = e0 + CHUNK_A; if (e1 > N_EDGES) e1 = N_EDGES;
    for (int e = e0 + t; e < e1; e += 256) {
        atomicAdd(&hist[col[e] >> BSHIFT], 1);
    }
    __syncthreads();
    ghistT[t * NBLK_A + blockIdx.x] = hist[t];
}

// ---------------- Phase A2a: per-bucket scan over 512 A-blocks ----------------
__global__ __launch_bounds__(256) void k_A2a(const int* __restrict__ ghistT, int* __restrict__ goffT,
                                             int* __restrict__ tot) {
    __shared__ int s[256];
    int b = blockIdx.x, t = threadIdx.x;
    int2 v = ((const int2*)(ghistT + b * NBLK_A))[t];
    int pair = v.x + v.y;
    s[t] = pair;
    __syncthreads();
    for (int d = 1; d < 256; d <<= 1) {
        int o = (t >= d) ? s[t - d] : 0;
        __syncthreads();
        s[t] += o;
        __syncthreads();
    }
    int incl = s[t];
    int excl = incl - pair;
    goffT[b * NBLK_A + 2 * t]     = excl;
    goffT[b * NBLK_A + 2 * t + 1] = excl + v.x;
    if (t == 255) tot[b] = incl;
}

// ---------------- Phase A2b: scan of bucket totals + sentinel zero + padded b2 ----------------
__global__ __launch_bounds__(256) void k_A2b(const int* __restrict__ tot, int* __restrict__ bbase,
                                             int* __restrict__ bend,
                                             unsigned char* __restrict__ h1q,
                                             unsigned char* __restrict__ h2q,
                                             const float* __restrict__ b2, float* __restrict__ pb2) {
    __shared__ int s[256];
    int t = threadIdx.x;
    int v = tot[t];
    s[t] = v;
    __syncthreads();
    for (int d = 1; d < 256; d <<= 1) {
        int o = (t >= d) ? s[t - d] : 0;
        __syncthreads();
        s[t] += o;
        __syncthreads();
    }
    bbase[t] = s[t] - v;
    bend[t] = s[t];
    if (t < 64) h1q[(size_t)ZROW * 64 + t] = 0;
    else if (t < 128) h2q[(size_t)ZROW * 64 + (t - 64)] = 0;
    else if (t < 192) pb2[t - 128] = (t - 128 < N_CLASS) ? b2[t - 128] : 0.f;
}

// ---------------- Phase A3: coalesced-reserved bucket scatter ----------------
__global__ __launch_bounds__(256) void k_A3(const int* __restrict__ row, const int* __restrict__ col,
                                            const int* __restrict__ goffT, const int* __restrict__ bbase,
                                            unsigned int* __restrict__ epair) {
    __shared__ int cur[256];
    int t = threadIdx.x;
    cur[t] = goffT[t * NBLK_A + blockIdx.x] + bbase[t];
    __syncthreads();
    int e0 = blockIdx.x * CHUNK_A;
    int e1 = e0 + CHUNK_A; if (e1 > N_EDGES) e1 = N_EDGES;
    for (int e = e0 + t; e < e1; e += 256) {
        int c = col[e];
        int pos = atomicAdd(&cur[c >> BSHIFT], 1);
        epair[pos] = ((unsigned int)(c & 511) << 17) | (unsigned int)row[e];
    }
}

// ---------------- Phase B: per-bucket CSR build; srow holds (row<<6) byte offsets ----------------
__global__ __launch_bounds__(256) void k_B(const unsigned int* __restrict__ epair,
                                           const int* __restrict__ bbase, const int* __restrict__ bend,
                                           int* __restrict__ off, int* __restrict__ pdeg,
                                           float* __restrict__ dinv, int* __restrict__ srow) {
    __shared__ int h[512];
    __shared__ int psc[256];
    int t = threadIdx.x;
    int b = blockIdx.x;
    int n0 = b << BSHIFT;
    int e0 = bbase[b], e1 = bend[b];
    int pbase = e0 + b * 4096;
    h[t] = 0; h[t + 256] = 0;
    __syncthreads();
    for (int e = e0 + t; e < e1; e += 256) {
        atomicAdd(&h[epair[e] >> 17], 1);
    }
    __syncthreads();
    int a0 = h[2 * t], a1 = h[2 * t + 1];
    int p0 = (a0 + 7) & ~7, p1 = (a1 + 7) & ~7;
    psc[t] = p0 + p1;
    __syncthreads();
    for (int d = 1; d < 256; d <<= 1) {
        int o = (t >= d) ? psc[t - d] : 0;
        __syncthreads();
        psc[t] += o;
        __syncthreads();
    }
    int base0 = pbase + psc[t] - (p0 + p1);
    int base1 = base0 + p0;
    h[2 * t] = base0;
    h[2 * t + 1] = base1;
    int n = n0 + 2 * t;
    const int zb = ZROW << 6;
    if (n < N_NODES) {
        off[n] = base0; pdeg[n] = p0; dinv[n] = rsqrtf((float)a0 + 1.0f);
        for (int p = a0; p < p0; ++p) srow[base0 + p] = zb;
    }
    if (n + 1 < N_NODES) {
        off[n + 1] = base1; pdeg[n + 1] = p1; dinv[n + 1] = rsqrtf((float)a1 + 1.0f);
        for (int p = a1; p < p1; ++p) srow[base1 + p] = zb;
    }
    __syncthreads();
    for (int e = e0 + t; e < e1; e += 256) {
        unsigned int k = epair[e];
        int c = k >> 17;
        int pos = atomicAdd(&h[c], 1);
        srow[pos] = (int)(k & 0x1FFFFu) << 6;
    }
}

// ---------------- layer-1 GEMM via MFMA bf16: h1q = fp8(dinv[n] * (X @ W1^T)) ----------------
// wave = 16 rows; A-frag: lane l holds x[rb+(l&15)][kk*32+(l>>4)*8+j]; B = W1^T in regs.
// D layout (verified): col = lane&15, row = (lane>>4)*4 + reg.
#define LDB1(CT, KK, VAR) { \
    int n = CT * 16 + m; \
    const float4* p = (const float4*)W + ((size_t)n * 32 + KK * 8 + g * 2); \
    float4 v0 = p[0], v1 = p[1]; \
    uint4 u; \
    u.x = cvtpk_bf16(v0.x, v0.y); u.y = cvtpk_bf16(v0.z, v0.w); \
    u.z = cvtpk_bf16(v1.x, v1.y); u.w = cvtpk_bf16(v1.z, v1.w); \
    VAR = *(bf16x8*)&u; }

#define STEP1(KK, B0, B1, B2, B3) { \
    float4 v0 = make_float4(0.f,0.f,0.f,0.f), v1 = make_float4(0.f,0.f,0.f,0.f); \
    if (ar < N_NODES) { \
        const float4* p = (const float4*)X + ((size_t)ar * 32 + KK * 8 + g * 2); \
        v0 = p[0]; v1 = p[1]; \
    } \
    uint4 u; \
    u.x = cvtpk_bf16(v0.x, v0.y); u.y = cvtpk_bf16(v0.z, v0.w); \
    u.z = cvtpk_bf16(v1.x, v1.y); u.w = cvtpk_bf16(v1.z, v1.w); \
    bf16x8 af = *(bf16x8*)&u; \
    ac0 = __builtin_amdgcn_mfma_f32_16x16x32_bf16(af, B0, ac0, 0, 0, 0); \
    ac1 = __builtin_amdgcn_mfma_f32_16x16x32_bf16(af, B1, ac1, 0, 0, 0); \
    ac2 = __builtin_amdgcn_mfma_f32_16x16x32_bf16(af, B2, ac2, 0, 0, 0); \
    ac3 = __builtin_amdgcn_mfma_f32_16x16x32_bf16(af, B3, ac3, 0, 0, 0); }

__global__ __launch_bounds__(256) void k_gemm1(const float* __restrict__ X, const float* __restrict__ W,
                                               const float* __restrict__ scale, unsigned char* __restrict__ O) {
    int t = threadIdx.x;
    int lane = t & 63, w = t >> 6;
    int m = lane & 15, g = lane >> 4;
    bf16x8 b00, b01, b02, b03, b10, b11, b12, b13, b20, b21, b22, b23, b30, b31, b32, b33;
    LDB1(0,0,b00) LDB1(0,1,b01) LDB1(0,2,b02) LDB1(0,3,b03)
    LDB1(1,0,b10) LDB1(1,1,b11) LDB1(1,2,b12) LDB1(1,3,b13)
    LDB1(2,0,b20) LDB1(2,1,b21) LDB1(2,2,b22) LDB1(2,3,b23)
    LDB1(3,0,b30) LDB1(3,1,b31) LDB1(3,2,b32) LDB1(3,3,b33)
    int rb = blockIdx.x * 64 + w * 16;
    int ar = rb + m;   // A row this lane loads
    f32x4v ac0 = {0.f,0.f,0.f,0.f}, ac1 = {0.f,0.f,0.f,0.f};
    f32x4v ac2 = {0.f,0.f,0.f,0.f}, ac3 = {0.f,0.f,0.f,0.f};
    STEP1(0, b00, b10, b20, b30)
    STEP1(1, b01, b11, b21, b31)
    STEP1(2, b02, b12, b22, b32)
    STEP1(3, b03, b13, b23, b33)
#pragma unroll
    for (int r = 0; r < 4; ++r) {
        int rr = rb + g * 4 + r;
        if (rr < N_NODES) {
            float sc = scale[rr];
            O[(size_t)rr * 64 +      m] = enc_fp8(ac0[r] * sc);
            O[(size_t)rr * 64 + 16 + m] = enc_fp8(ac1[r] * sc);
            O[(size_t)rr * 64 + 32 + m] = enc_fp8(ac2[r] * sc);
            O[(size_t)rr * 64 + 48 + m] = enc_fp8(ac3[r] * sc);
        }
    }
}

// ---------------- layer-2 GEMM via MFMA bf16: h2q = fp8(8 * (o1b @ W2^T)) ----------------
#define LDB2(CT, KK, VAR) { \
    int n = CT * 16 + m; \
    float4 v0 = make_float4(0.f,0.f,0.f,0.f), v1 = make_float4(0.f,0.f,0.f,0.f); \
    if (n < N_CLASS) { \
        const float4* p = (const float4*)W2 + ((size_t)n * 16 + KK * 8 + g * 2); \
        v0 = p[0]; v1 = p[1]; \
    } \
    uint4 u; \
    u.x = cvtpk_bf16(v0.x * 8.f, v0.y * 8.f); u.y = cvtpk_bf16(v0.z * 8.f, v0.w * 8.f); \
    u.z = cvtpk_bf16(v1.x * 8.f, v1.y * 8.f); u.w = cvtpk_bf16(v1.z * 8.f, v1.w * 8.f); \
    VAR = *(bf16x8*)&u; }

#define STEP2(KK, B0, B1, B2, B3) { \
    uint4 u = make_uint4(0u,0u,0u,0u); \
    if (ar < N_NODES) u = *(const uint4*)(o1b + ((size_t)ar * 64 + KK * 32 + g * 8)); \
    bf16x8 af = *(bf16x8*)&u; \
    ac0 = __builtin_amdgcn_mfma_f32_16x16x32_bf16(af, B0, ac0, 0, 0, 0); \
    ac1 = __builtin_amdgcn_mfma_f32_16x16x32_bf16(af, B1, ac1, 0, 0, 0); \
    ac2 = __builtin_amdgcn_mfma_f32_16x16x32_bf16(af, B2, ac2, 0, 0, 0); \
    ac3 = __builtin_amdgcn_mfma_f32_16x16x32_bf16(af, B3, ac3, 0, 0, 0); }

__global__ __launch_bounds__(256) void k_gemm2(const unsigned short* __restrict__ o1b,
                                               const float* __restrict__ W2,
                                               unsigned char* __restrict__ h2q) {
    int t = threadIdx.x;
    int lane = t & 63, w = t >> 6;
    int m = lane & 15, g = lane >> 4;
    bf16x8 b00, b01, b10, b11, b20, b21, b30, b31;
    LDB2(0,0,b00) LDB2(0,1,b01) LDB2(1,0,b10) LDB2(1,1,b11)
    LDB2(2,0,b20) LDB2(2,1,b21) LDB2(3,0,b30) LDB2(3,1,b31)
    int rb = blockIdx.x * 64 + w * 16;
    int ar = rb + m;
    f32x4v ac0 = {0.f,0.f,0.f,0.f}, ac1 = {0.f,0.f,0.f,0.f};
    f32x4v ac2 = {0.f,0.f,0.f,0.f}, ac3 = {0.f,0.f,0.f,0.f};
    STEP2(0, b00, b10, b20, b30)
    STEP2(1, b01, b11, b21, b31)
#pragma unroll
    for (int r = 0; r < 4; ++r) {
        int rr = rb + g * 4 + r;
        if (rr < N_NODES) {
            h2q[(size_t)rr * 64 +      m] = enc_fp8(ac0[r]);
            h2q[(size_t)rr * 64 + 16 + m] = enc_fp8(ac1[r]);
            h2q[(size_t)rr * 64 + 32 + m] = enc_fp8(ac2[r]);
            h2q[(size_t)rr * 64 + 48 + m] = enc_fp8(ac3[r]);
        }
    }
}

// ---------------- layer-1 aggregation: 8 nodes/wave -> o1b bf16 ----------------
__global__ __launch_bounds__(256) void k_agg1(const int* __restrict__ off, const int* __restrict__ pdeg,
                                              const int* __restrict__ srow, const float* __restrict__ dinv,
                                              const unsigned char* __restrict__ h1q, const float* __restrict__ b1,
                                              unsigned short* __restrict__ o1b) {
    int t = threadIdx.x;
    int lane = t & 63;
    int e = lane >> 3, seg = lane & 7;
    int node = ((blockIdx.x * 256 + t) >> 6) * 8 + e;   // 8 consecutive nodes per wave
    int myoff = off[node];
    int mydeg = pdeg[node];
    GATHER_PL(h1q)
    float dc = dinv[node];
    float4 ba = *(const float4*)(b1 + seg * 8);
    float4 bb4 = *(const float4*)(b1 + seg * 8 + 4);
    float v0 = dc * a01.x + ba.x,  v1 = dc * a01.y + ba.y;
    float v2 = dc * a23.x + ba.z,  v3 = dc * a23.y + ba.w;
    float v4 = dc * a45.x + bb4.x, v5 = dc * a45.y + bb4.y;
    float v6 = dc * a67.x + bb4.z, v7 = dc * a67.y + bb4.w;
    v0 = v0 > 0.f ? v0 * dc : 0.f; v1 = v1 > 0.f ? v1 * dc : 0.f;
    v2 = v2 > 0.f ? v2 * dc : 0.f; v3 = v3 > 0.f ? v3 * dc : 0.f;
    v4 = v4 > 0.f ? v4 * dc : 0.f; v5 = v5 > 0.f ? v5 * dc : 0.f;
    v6 = v6 > 0.f ? v6 * dc : 0.f; v7 = v7 > 0.f ? v7 * dc : 0.f;
    uint4 pk;
    pk.x = cvtpk_bf16(v0, v1); pk.y = cvtpk_bf16(v2, v3);
    pk.z = cvtpk_bf16(v4, v5); pk.w = cvtpk_bf16(v6, v7);
    *(uint4*)(o1b + ((size_t)node * 64 + seg * 8)) = pk;
}

// ---------------- layer-2 aggregation: 8 nodes/wave + per-group softmax/argmax ----------------
__global__ __launch_bounds__(256) void k_agg2(const int* __restrict__ off, const int* __restrict__ pdeg,
                                              const int* __restrict__ srow, const float* __restrict__ dinv,
                                              const unsigned char* __restrict__ h2q,
                                              const float* __restrict__ pb2, const int* __restrict__ y,
                                              float* __restrict__ out, unsigned short* __restrict__ ps) {
    int t = threadIdx.x;
    int lane = t & 63;
    int e = lane >> 3, seg = lane & 7;
    int node = ((blockIdx.x * 256 + t) >> 6) * 8 + e;
    int myoff = off[node];
    int mydeg = pdeg[node];
    GATHER_PL(h2q)
    float dc = dinv[node] * 0.125f;   // undo the x8 h2q scale
    float4 ba = *(const float4*)(pb2 + seg * 8);
    float4 bb4 = *(const float4*)(pb2 + seg * 8 + 4);
    bool act = seg < 5;               // classes seg*8..seg*8+7, 40 = 5*8
    float v0 = act ? (dc * a01.x + ba.x)  : -1e30f;
    float v1 = act ? (dc * a01.y + ba.y)  : -1e30f;
    float v2 = act ? (dc * a23.x + ba.z)  : -1e30f;
    float v3 = act ? (dc * a23.y + ba.w)  : -1e30f;
    float v4 = act ? (dc * a45.x + bb4.x) : -1e30f;
    float v5 = act ? (dc * a45.y + bb4.y) : -1e30f;
    float v6 = act ? (dc * a67.x + bb4.z) : -1e30f;
    float v7 = act ? (dc * a67.y + bb4.w) : -1e30f;
    // per-lane max + first-occurrence argmax over this lane's 8 classes
    float m = v0; int aj = 0;
    if (v1 > m) { m = v1; aj = 1; }
    if (v2 > m) { m = v2; aj = 2; }
    if (v3 > m) { m = v3; aj = 3; }
    if (v4 > m) { m = v4; aj = 4; }
    if (v5 > m) { m = v5; aj = 5; }
    if (v6 > m) { m = v6; aj = 6; }
    if (v7 > m) { m = v7; aj = 7; }
    int ac = seg * 8 + aj;
#pragma unroll
    for (int k = 1; k < 8; k <<= 1) {   // reduce within the 8-lane e-group
        float om = __shfl_xor(m, k);
        int oc = __shfl_xor(ac, k);
        if (om > m || (om == m && oc < ac)) { m = om; ac = oc; }
    }
    float s = 0.f;
    if (act) {
        s = expf(v0 - m) + expf(v1 - m) + expf(v2 - m) + expf(v3 - m)
          + expf(v4 - m) + expf(v5 - m) + expf(v6 - m) + expf(v7 - m);
    }
#pragma unroll
    for (int k = 1; k < 8; k <<= 1) s += __shfl_xor(s, k);
    float ls = logf(s);
    if (act) {
        float lp0 = (v0 - m) - ls, lp1 = (v1 - m) - ls, lp2 = (v2 - m) - ls, lp3 = (v3 - m) - ls;
        float lp4 = (v4 - m) - ls, lp5 = (v5 - m) - ls, lp6 = (v6 - m) - ls, lp7 = (v7 - m) - ls;
        float* logp = out + (size_t)node * N_CLASS + seg * 8;
        *(float4*)logp       = make_float4(lp0, lp1, lp2, lp3);
        *(float4*)(logp + 4) = make_float4(lp4, lp5, lp6, lp7);
        float* pp = out + (size_t)N_NODES * N_CLASS + (size_t)node * N_CLASS + seg * 8;
        *(float4*)pp       = make_float4(expf(lp0), expf(lp1), expf(lp2), expf(lp3));
        *(float4*)(pp + 4) = make_float4(expf(lp4), expf(lp5), expf(lp6), expf(lp7));
    }
    if (seg == 0) ps[node] = (unsigned short)((y[node] << 8) | ac);
}

// ---------------- ratio: software-pipelined, ~3 iterations/thread ----------------
#define RATIO_BLOCKS 512
__global__ __launch_bounds__(256) void k_ratio(const int* __restrict__ row, const int* __restrict__ col,
                                               const unsigned short* __restrict__ ps,
                                               unsigned int* __restrict__ cnt) {
    const int G = N_EDGES / 8;
    int i = blockIdx.x * 256 + threadIdx.x;
    int stride = RATIO_BLOCKS * 256;
    unsigned int local = 0;
    int e8 = i;
    if (e8 < G) {
        int4 ra = ((const int4*)row)[e8 * 2];
        int4 rb = ((const int4*)row)[e8 * 2 + 1];
        int4 ca = ((const int4*)col)[e8 * 2];
        int4 cb = ((const int4*)col)[e8 * 2 + 1];
        for (;;) {
            int en = e8 + stride;
            bool more = en < G;
            int4 nra, nrb, nca, ncb;
            if (more) {                      // issue next iteration's edge loads now
                nra = ((const int4*)row)[en * 2];
                nrb = ((const int4*)row)[en * 2 + 1];
                nca = ((const int4*)col)[en * 2];
                ncb = ((const int4*)col)[en * 2 + 1];
            }
            unsigned int pa[8], pb[8];       // 16 independent gathers in flight
            pa[0] = ps[ra.x]; pa[1] = ps[ra.y]; pa[2] = ps[ra.z]; pa[3] = ps[ra.w];
            pa[4] = ps[rb.x]; pa[5] = ps[rb.y]; pa[6] = ps[rb.z]; pa[7] = ps[rb.w];
            pb[0] = ps[ca.x]; pb[1] = ps[ca.y]; pb[2] = ps[ca.z]; pb[3] = ps[ca.w];
            pb[4] = ps[cb.x]; pb[5] = ps[cb.y]; pb[6] = ps[cb.z]; pb[7] = ps[cb.w];
#pragma unroll
            for (int k = 0; k < 8; ++k) {
                bool sp = (pa[k] & 0xffu) == (pb[k] & 0xffu);
                bool sy = (pa[k] >> 8) == (pb[k] >> 8);
                local += (sp == sy) ? 1u : 0u;
            }
            if (!more) break;
            ra = nra; rb = nrb; ca = nca; cb = ncb;
            e8 = en;
        }
    }
    if (local) atomicAdd(cnt, local);
}

__global__ void k_fin(const unsigned int* __restrict__ cnt, float* __restrict__ out) {
    out[0] = (float)(*cnt) / (float)N_EDGES;
}

extern "C" void kernel_launch(void* const* d_in, const int* in_sizes, int n_in,
                              void* d_out, int out_size, void* d_ws, size_t ws_size,
                              hipStream_t stream) {
    const float* x  = (const float*)d_in[0];
    const int*   ei = (const int*)d_in[1];
    const int*   y  = (const int*)d_in[2];
    const float* W1 = (const float*)d_in[3];
    const float* b1 = (const float*)d_in[4];
    const float* W2 = (const float*)d_in[5];
    const float* b2 = (const float*)d_in[6];

    const int* row = ei;
    const int* col = ei + N_EDGES;

    float* ws = (float*)d_ws;
    // workspace layout (4B units); fp8 tables have N_NODES+1 rows (sentinel)
    unsigned char* h1q = (unsigned char*)ws;               // (N+1)*64 B
    unsigned char* h2q = (unsigned char*)(ws + 1700000);   // (N+1)*64 B
    float* dinv   = ws + 3400000;                   // N
    int*   pdeg   = (int*)(ws + 3500000);           // N
    int*   off    = (int*)(ws + 3600000);           // N
    int*   srow   = (int*)(ws + 3700000);           // padded CSR (~4.0M) + tail slack
    int*   ghistT = (int*)(ws + 7800000);           // 256*512 (bucket-major)
    int*   goffT  = (int*)(ws + 8000000);           // 256*512
    int*   tot    = (int*)(ws + 8150000);           // 256
    int*   bbase  = (int*)(ws + 8200000);           // 256
    int*   bend   = (int*)(ws + 8201000);           // 256
    float* pb2    = ws + 8202000;                   // 64 (padded b2)
    unsigned short* ps = (unsigned short*)(ws + 8210000);  // N ushort
    unsigned int* cnt  = (unsigned int*)(ws + 8300000);
    unsigned int* epair = (unsigned int*)(ws + 8400000);   // E uint32 (ends ~11.6M)
    unsigned short* o1b = (unsigned short*)(ws + 11700000); // N*64 bf16 (12.8 MB)

    float* out = (float*)d_out;

    (void)hipMemsetAsync(cnt, 0, 4, stream);

    const int GEMM_GRID = (N_NODES + 63) / 64;      // 1563 blocks, 64 rows each
    const int AGG_GRID = N_NODES / 32;              // 8 nodes/wave * 4 waves = 32 nodes/block

    k_A1<<<NBLK_A, 256, 0, stream>>>(col, ghistT);
    k_A2a<<<256, 256, 0, stream>>>(ghistT, goffT, tot);
    k_A2b<<<1, 256, 0, stream>>>(tot, bbase, bend, h1q, h2q, b2, pb2);
    k_A3<<<NBLK_A, 256, 0, stream>>>(row, col, goffT, bbase, epair);
    k_B<<<NBUCK, 256, 0, stream>>>(epair, bbase, bend, off, pdeg, dinv, srow);
    k_gemm1<<<GEMM_GRID, 256, 0, stream>>>(x, W1, dinv, h1q);
    k_agg1<<<AGG_GRID, 256, 0, stream>>>(off, pdeg, srow, dinv, h1q, b1, o1b);
    k_gemm2<<<GEMM_GRID, 256, 0, stream>>>(o1b, W2, h2q);
    k_agg2<<<AGG_GRID, 256, 0, stream>>>(off, pdeg, srow, dinv, h2q, pb2, y, out, ps);
    k_ratio<<<RATIO_BLOCKS, 256, 0, stream>>>(row, col, ps, cnt);
    k_fin<<<1, 1, 0, stream>>>(cnt, out + (size_t)2 * N_NODES * N_CLASS);
}

// Round 24
// 274.522 us; speedup vs baseline: 1.5257x; 1.0141x over previous
//
#include <hip/hip_runtime.h>

#define N_NODES 100000
#define N_EDGES 3200000
#define F_IN 128
#define HID 64
#define N_CLASS 40
#define ZROW N_NODES       // sentinel zero-row index

#define NBUCK 196          // ceil(100000/512)
#define BSHIFT 9
#define NBLK_A 512
#define CHUNK_A ((N_EDGES + NBLK_A - 1) / NBLK_A)

typedef float f32x2 __attribute__((ext_vector_type(2)));
typedef __attribute__((ext_vector_type(8))) short bf16x8;
typedef __attribute__((ext_vector_type(4))) float f32x4v;

static __device__ __forceinline__ unsigned char enc_fp8(float v) {
    return (unsigned char)(__builtin_amdgcn_cvt_pk_fp8_f32(v, v, 0, false) & 0xff);
}
static __device__ __forceinline__ unsigned cvtpk_bf16(float lo, float hi) {
    unsigned r;
    asm("v_cvt_pk_bf16_f32 %0, %1, %2" : "=v"(r) : "v"(lo), "v"(hi));
    return r;
}

// gather 8 fp8 bytes: byteoff = row<<6 (pre-shifted), seg in [0,8)
static __device__ __forceinline__ uint2 gat8(const unsigned char* base, int byteoff, int seg) {
    return *(const uint2*)(base + ((unsigned)byteoff | (unsigned)(seg << 3)));
}

// decode 8 fp8 (uint2), packed-f32 accumulate
#define CONS(RAW) do { \
    f32x2 f0 = __builtin_amdgcn_cvt_pk_f32_fp8((int)RAW.x, false); \
    f32x2 f1 = __builtin_amdgcn_cvt_pk_f32_fp8((int)RAW.x, true); \
    f32x2 f2 = __builtin_amdgcn_cvt_pk_f32_fp8((int)RAW.y, false); \
    f32x2 f3 = __builtin_amdgcn_cvt_pk_f32_fp8((int)RAW.y, true); \
    a01 += f0; a23 += f1; a45 += f2; a67 += f3; } while (0)

// 12-deep pipelined slot: consume G (edge bb+s of MY node), issue edge bb+12+s,
// reload C with idx for edge bb+24+s (address clamped to my range)
#define SLOTP(s, G, C) { \
    int ib = bb + 12 + s; \
    int srcr = (ib < mydeg) ? C : zb; \
    uint2 ng = gat8(gsrc, srcr, seg); \
    C = sp[min(bb + 24 + s, mlast)]; \
    __builtin_amdgcn_sched_barrier(0); \
    CONS(G); \
    G = ng; }

#define PRO(s, G, C) \
    uint2 G = gat8(gsrc, (s < mydeg) ? sp[min(s, mlast)] : zb, seg); \
    int C = sp[min(12 + s, mlast)];

// per-lane gather phase: each lane owns node `node` (e-group) and features seg*8..+7.
#define GATHER_PL(TBL) \
    f32x2 a01 = {0.f, 0.f}, a23 = {0.f, 0.f}, a45 = {0.f, 0.f}, a67 = {0.f, 0.f}; \
    { \
        const unsigned char* gsrc = TBL; \
        const int* sp = srow + myoff; \
        const int zb = ZROW << 6; \
        int nbmax = mydeg; \
        nbmax = max(nbmax, __shfl_xor(nbmax, 8)); \
        nbmax = max(nbmax, __shfl_xor(nbmax, 16)); \
        nbmax = max(nbmax, __shfl_xor(nbmax, 32)); \
        if (nbmax > 0) { \
            int mlast = mydeg > 0 ? mydeg - 1 : 0; \
            PRO(0, g0, c0)  PRO(1, g1, c1)  PRO(2, g2, c2)  PRO(3, g3, c3) \
            PRO(4, g4, c4)  PRO(5, g5, c5)  PRO(6, g6, c6)  PRO(7, g7, c7) \
            PRO(8, g8, c8)  PRO(9, g9, c9)  PRO(10, g10, c10) PRO(11, g11, c11) \
            for (int bb = 0; bb < nbmax; bb += 12) { \
                SLOTP(0, g0, c0)  SLOTP(1, g1, c1)  SLOTP(2, g2, c2) \
                SLOTP(3, g3, c3)  SLOTP(4, g4, c4)  SLOTP(5, g5, c5) \
                SLOTP(6, g6, c6)  SLOTP(7, g7, c7)  SLOTP(8, g8, c8) \
                SLOTP(9, g9, c9)  SLOTP(10, g10, c10) SLOTP(11, g11, c11) \
            } \
        } \
        /* self term: every lane adds its own node's segment once */ \
        uint2 sg = gat8(gsrc, node << 6, seg); \
        CONS(sg); \
    }

// ---------------- Phase A1: per-block bucket histogram (transposed out) ----------------
__global__ __launch_bounds__(256) void k_A1(const int* __restrict__ col, int* __restrict__ ghistT) {
    __shared__ int hist[256];
    int t = threadIdx.x;
    hist[t] = 0;
    __syncthreads();
    int e0 = blockIdx.x * CHUNK_A;
    int e1 = e0 + CHUNK_A; if (e1 > N_EDGES) e1 = N_EDGES;
    for (int e = e0 + t; e < e1; e += 256) {
        atomicAdd(&hist[col[e] >> BSHIFT], 1);
    }
    __syncthreads();
    ghistT[t * NBLK_A + blockIdx.x] = hist[t];
}

// ---------------- Phase A2a: per-bucket scan over 512 A-blocks ----------------
__global__ __launch_bounds__(256) void k_A2a(const int* __restrict__ ghistT, int* __restrict__ goffT,
                                             int* __restrict__ tot) {
    __shared__ int s[256];
    int b = blockIdx.x, t = threadIdx.x;
    int2 v = ((const int2*)(ghistT + b * NBLK_A))[t];
    int pair = v.x + v.y;
    s[t] = pair;
    __syncthreads();
    for (int d = 1; d < 256; d <<= 1) {
        int o = (t >= d) ? s[t - d] : 0;
        __syncthreads();
        s[t] += o;
        __syncthreads();
    }
    int incl = s[t];
    int excl = incl - pair;
    goffT[b * NBLK_A + 2 * t]     = excl;
    goffT[b * NBLK_A + 2 * t + 1] = excl + v.x;
    if (t == 255) tot[b] = incl;
}

// ---------------- Phase A2b: scan of bucket totals + sentinel zero + padded b2 ----------------
__global__ __launch_bounds__(256) void k_A2b(const int* __restrict__ tot, int* __restrict__ bbase,
                                             int* __restrict__ bend,
                                             unsigned char* __restrict__ h1q,
                                             unsigned char* __restrict__ h2q,
                                             const float* __restrict__ b2, float* __restrict__ pb2) {
    __shared__ int s[256];
    int t = threadIdx.x;
    int v = tot[t];
    s[t] = v;
    __syncthreads();
    for (int d = 1; d < 256; d <<= 1) {
        int o = (t >= d) ? s[t - d] : 0;
        __syncthreads();
        s[t] += o;
        __syncthreads();
    }
    bbase[t] = s[t] - v;
    bend[t] = s[t];
    if (t < 64) h1q[(size_t)ZROW * 64 + t] = 0;
    else if (t < 128) h2q[(size_t)ZROW * 64 + (t - 64)] = 0;
    else if (t < 192) pb2[t - 128] = (t - 128 < N_CLASS) ? b2[t - 128] : 0.f;
}

// ---------------- Phase A3: coalesced-reserved bucket scatter ----------------
__global__ __launch_bounds__(256) void k_A3(const int* __restrict__ row, const int* __restrict__ col,
                                            const int* __restrict__ goffT, const int* __restrict__ bbase,
                                            unsigned int* __restrict__ epair) {
    __shared__ int cur[256];
    int t = threadIdx.x;
    cur[t] = goffT[t * NBLK_A + blockIdx.x] + bbase[t];
    __syncthreads();
    int e0 = blockIdx.x * CHUNK_A;
    int e1 = e0 + CHUNK_A; if (e1 > N_EDGES) e1 = N_EDGES;
    for (int e = e0 + t; e < e1; e += 256) {
        int c = col[e];
        int pos = atomicAdd(&cur[c >> BSHIFT], 1);
        epair[pos] = ((unsigned int)(c & 511) << 17) | (unsigned int)row[e];
    }
}

// ---------------- Phase B: per-bucket CSR build; srow holds (row<<6) byte offsets ----------------
__global__ __launch_bounds__(256) void k_B(const unsigned int* __restrict__ epair,
                                           const int* __restrict__ bbase, const int* __restrict__ bend,
                                           int* __restrict__ off, int* __restrict__ pdeg,
                                           float* __restrict__ dinv, int* __restrict__ srow) {
    __shared__ int h[512];
    __shared__ int psc[256];
    int t = threadIdx.x;
    int b = blockIdx.x;
    int n0 = b << BSHIFT;
    int e0 = bbase[b], e1 = bend[b];
    int pbase = e0 + b * 4096;
    h[t] = 0; h[t + 256] = 0;
    __syncthreads();
    for (int e = e0 + t; e < e1; e += 256) {
        atomicAdd(&h[epair[e] >> 17], 1);
    }
    __syncthreads();
    int a0 = h[2 * t], a1 = h[2 * t + 1];
    int p0 = (a0 + 7) & ~7, p1 = (a1 + 7) & ~7;
    psc[t] = p0 + p1;
    __syncthreads();
    for (int d = 1; d < 256; d <<= 1) {
        int o = (t >= d) ? psc[t - d] : 0;
        __syncthreads();
        psc[t] += o;
        __syncthreads();
    }
    int base0 = pbase + psc[t] - (p0 + p1);
    int base1 = base0 + p0;
    h[2 * t] = base0;
    h[2 * t + 1] = base1;
    int n = n0 + 2 * t;
    const int zb = ZROW << 6;
    if (n < N_NODES) {
        off[n] = base0; pdeg[n] = p0; dinv[n] = rsqrtf((float)a0 + 1.0f);
        for (int p = a0; p < p0; ++p) srow[base0 + p] = zb;
    }
    if (n + 1 < N_NODES) {
        off[n + 1] = base1; pdeg[n + 1] = p1; dinv[n + 1] = rsqrtf((float)a1 + 1.0f);
        for (int p = a1; p < p1; ++p) srow[base1 + p] = zb;
    }
    __syncthreads();
    for (int e = e0 + t; e < e1; e += 256) {
        unsigned int k = epair[e];
        int c = k >> 17;
        int pos = atomicAdd(&h[c], 1);
        srow[pos] = (int)(k & 0x1FFFFu) << 6;
    }
}

// ---------------- layer-1 GEMM via MFMA bf16: h1q = fp8(dinv[n] * (X @ W1^T)) ----------------
#define LDB1(CT, KK, VAR) { \
    int n = CT * 16 + m; \
    const float4* p = (const float4*)W + ((size_t)n * 32 + KK * 8 + g * 2); \
    float4 v0 = p[0], v1 = p[1]; \
    uint4 u; \
    u.x = cvtpk_bf16(v0.x, v0.y); u.y = cvtpk_bf16(v0.z, v0.w); \
    u.z = cvtpk_bf16(v1.x, v1.y); u.w = cvtpk_bf16(v1.z, v1.w); \
    VAR = *(bf16x8*)&u; }

#define STEP1(KK, B0, B1, B2, B3) { \
    float4 v0 = make_float4(0.f,0.f,0.f,0.f), v1 = make_float4(0.f,0.f,0.f,0.f); \
    if (ar < N_NODES) { \
        const float4* p = (const float4*)X + ((size_t)ar * 32 + KK * 8 + g * 2); \
        v0 = p[0]; v1 = p[1]; \
    } \
    uint4 u; \
    u.x = cvtpk_bf16(v0.x, v0.y); u.y = cvtpk_bf16(v0.z, v0.w); \
    u.z = cvtpk_bf16(v1.x, v1.y); u.w = cvtpk_bf16(v1.z, v1.w); \
    bf16x8 af = *(bf16x8*)&u; \
    ac0 = __builtin_amdgcn_mfma_f32_16x16x32_bf16(af, B0, ac0, 0, 0, 0); \
    ac1 = __builtin_amdgcn_mfma_f32_16x16x32_bf16(af, B1, ac1, 0, 0, 0); \
    ac2 = __builtin_amdgcn_mfma_f32_16x16x32_bf16(af, B2, ac2, 0, 0, 0); \
    ac3 = __builtin_amdgcn_mfma_f32_16x16x32_bf16(af, B3, ac3, 0, 0, 0); }

__global__ __launch_bounds__(256) void k_gemm1(const float* __restrict__ X, const float* __restrict__ W,
                                               const float* __restrict__ scale, unsigned char* __restrict__ O) {
    int t = threadIdx.x;
    int lane = t & 63, w = t >> 6;
    int m = lane & 15, g = lane >> 4;
    bf16x8 b00, b01, b02, b03, b10, b11, b12, b13, b20, b21, b22, b23, b30, b31, b32, b33;
    LDB1(0,0,b00) LDB1(0,1,b01) LDB1(0,2,b02) LDB1(0,3,b03)
    LDB1(1,0,b10) LDB1(1,1,b11) LDB1(1,2,b12) LDB1(1,3,b13)
    LDB1(2,0,b20) LDB1(2,1,b21) LDB1(2,2,b22) LDB1(2,3,b23)
    LDB1(3,0,b30) LDB1(3,1,b31) LDB1(3,2,b32) LDB1(3,3,b33)
    int rb = blockIdx.x * 64 + w * 16;
    int ar = rb + m;   // A row this lane loads
    f32x4v ac0 = {0.f,0.f,0.f,0.f}, ac1 = {0.f,0.f,0.f,0.f};
    f32x4v ac2 = {0.f,0.f,0.f,0.f}, ac3 = {0.f,0.f,0.f,0.f};
    STEP1(0, b00, b10, b20, b30)
    STEP1(1, b01, b11, b21, b31)
    STEP1(2, b02, b12, b22, b32)
    STEP1(3, b03, b13, b23, b33)
#pragma unroll
    for (int r = 0; r < 4; ++r) {
        int rr = rb + g * 4 + r;
        if (rr < N_NODES) {
            float sc = scale[rr];
            O[(size_t)rr * 64 +      m] = enc_fp8(ac0[r] * sc);
            O[(size_t)rr * 64 + 16 + m] = enc_fp8(ac1[r] * sc);
            O[(size_t)rr * 64 + 32 + m] = enc_fp8(ac2[r] * sc);
            O[(size_t)rr * 64 + 48 + m] = enc_fp8(ac3[r] * sc);
        }
    }
}

// ---------------- layer-2 GEMM via MFMA bf16: h2q = fp8(8 * (o1b @ W2^T)) ----------------
#define LDB2(CT, KK, VAR) { \
    int n = CT * 16 + m; \
    float4 v0 = make_float4(0.f,0.f,0.f,0.f), v1 = make_float4(0.f,0.f,0.f,0.f); \
    if (n < N_CLASS) { \
        const float4* p = (const float4*)W2 + ((size_t)n * 16 + KK * 8 + g * 2); \
        v0 = p[0]; v1 = p[1]; \
    } \
    uint4 u; \
    u.x = cvtpk_bf16(v0.x * 8.f, v0.y * 8.f); u.y = cvtpk_bf16(v0.z * 8.f, v0.w * 8.f); \
    u.z = cvtpk_bf16(v1.x * 8.f, v1.y * 8.f); u.w = cvtpk_bf16(v1.z * 8.f, v1.w * 8.f); \
    VAR = *(bf16x8*)&u; }

#define STEP2(KK, B0, B1, B2, B3) { \
    uint4 u = make_uint4(0u,0u,0u,0u); \
    if (ar < N_NODES) u = *(const uint4*)(o1b + ((size_t)ar * 64 + KK * 32 + g * 8)); \
    bf16x8 af = *(bf16x8*)&u; \
    ac0 = __builtin_amdgcn_mfma_f32_16x16x32_bf16(af, B0, ac0, 0, 0, 0); \
    ac1 = __builtin_amdgcn_mfma_f32_16x16x32_bf16(af, B1, ac1, 0, 0, 0); \
    ac2 = __builtin_amdgcn_mfma_f32_16x16x32_bf16(af, B2, ac2, 0, 0, 0); \
    ac3 = __builtin_amdgcn_mfma_f32_16x16x32_bf16(af, B3, ac3, 0, 0, 0); }

__global__ __launch_bounds__(256) void k_gemm2(const unsigned short* __restrict__ o1b,
                                               const float* __restrict__ W2,
                                               unsigned char* __restrict__ h2q) {
    int t = threadIdx.x;
    int lane = t & 63, w = t >> 6;
    int m = lane & 15, g = lane >> 4;
    bf16x8 b00, b01, b10, b11, b20, b21, b30, b31;
    LDB2(0,0,b00) LDB2(0,1,b01) LDB2(1,0,b10) LDB2(1,1,b11)
    LDB2(2,0,b20) LDB2(2,1,b21) LDB2(3,0,b30) LDB2(3,1,b31)
    int rb = blockIdx.x * 64 + w * 16;
    int ar = rb + m;
    f32x4v ac0 = {0.f,0.f,0.f,0.f}, ac1 = {0.f,0.f,0.f,0.f};
    f32x4v ac2 = {0.f,0.f,0.f,0.f}, ac3 = {0.f,0.f,0.f,0.f};
    STEP2(0, b00, b10, b20, b30)
    STEP2(1, b01, b11, b21, b31)
#pragma unroll
    for (int r = 0; r < 4; ++r) {
        int rr = rb + g * 4 + r;
        if (rr < N_NODES) {
            h2q[(size_t)rr * 64 +      m] = enc_fp8(ac0[r]);
            h2q[(size_t)rr * 64 + 16 + m] = enc_fp8(ac1[r]);
            h2q[(size_t)rr * 64 + 32 + m] = enc_fp8(ac2[r]);
            h2q[(size_t)rr * 64 + 48 + m] = enc_fp8(ac3[r]);
        }
    }
}

// ---------------- layer-1 aggregation: 8 nodes/wave -> o1b bf16 ----------------
__global__ __launch_bounds__(256) void k_agg1(const int* __restrict__ off, const int* __restrict__ pdeg,
                                              const int* __restrict__ srow, const float* __restrict__ dinv,
                                              const unsigned char* __restrict__ h1q, const float* __restrict__ b1,
                                              unsigned short* __restrict__ o1b) {
    int t = threadIdx.x;
    int lane = t & 63;
    int e = lane >> 3, seg = lane & 7;
    int node = ((blockIdx.x * 256 + t) >> 6) * 8 + e;   // 8 consecutive nodes per wave
    int myoff = off[node];
    int mydeg = pdeg[node];
    GATHER_PL(h1q)
    float dc = dinv[node];
    float4 ba = *(const float4*)(b1 + seg * 8);
    float4 bb4 = *(const float4*)(b1 + seg * 8 + 4);
    float v0 = dc * a01.x + ba.x,  v1 = dc * a01.y + ba.y;
    float v2 = dc * a23.x + ba.z,  v3 = dc * a23.y + ba.w;
    float v4 = dc * a45.x + bb4.x, v5 = dc * a45.y + bb4.y;
    float v6 = dc * a67.x + bb4.z, v7 = dc * a67.y + bb4.w;
    v0 = v0 > 0.f ? v0 * dc : 0.f; v1 = v1 > 0.f ? v1 * dc : 0.f;
    v2 = v2 > 0.f ? v2 * dc : 0.f; v3 = v3 > 0.f ? v3 * dc : 0.f;
    v4 = v4 > 0.f ? v4 * dc : 0.f; v5 = v5 > 0.f ? v5 * dc : 0.f;
    v6 = v6 > 0.f ? v6 * dc : 0.f; v7 = v7 > 0.f ? v7 * dc : 0.f;
    uint4 pk;
    pk.x = cvtpk_bf16(v0, v1); pk.y = cvtpk_bf16(v2, v3);
    pk.z = cvtpk_bf16(v4, v5); pk.w = cvtpk_bf16(v6, v7);
    *(uint4*)(o1b + ((size_t)node * 64 + seg * 8)) = pk;
}

// ---------------- layer-2 aggregation: 8 nodes/wave + per-group softmax/argmax ----------------
__global__ __launch_bounds__(256) void k_agg2(const int* __restrict__ off, const int* __restrict__ pdeg,
                                              const int* __restrict__ srow, const float* __restrict__ dinv,
                                              const unsigned char* __restrict__ h2q,
                                              const float* __restrict__ pb2, const int* __restrict__ y,
                                              float* __restrict__ out, unsigned short* __restrict__ ps) {
    int t = threadIdx.x;
    int lane = t & 63;
    int e = lane >> 3, seg = lane & 7;
    int node = ((blockIdx.x * 256 + t) >> 6) * 8 + e;
    int myoff = off[node];
    int mydeg = pdeg[node];
    GATHER_PL(h2q)
    float dc = dinv[node] * 0.125f;   // undo the x8 h2q scale
    float4 ba = *(const float4*)(pb2 + seg * 8);
    float4 bb4 = *(const float4*)(pb2 + seg * 8 + 4);
    bool act = seg < 5;               // classes seg*8..seg*8+7, 40 = 5*8
    float v0 = act ? (dc * a01.x + ba.x)  : -1e30f;
    float v1 = act ? (dc * a01.y + ba.y)  : -1e30f;
    float v2 = act ? (dc * a23.x + ba.z)  : -1e30f;
    float v3 = act ? (dc * a23.y + ba.w)  : -1e30f;
    float v4 = act ? (dc * a45.x + bb4.x) : -1e30f;
    float v5 = act ? (dc * a45.y + bb4.y) : -1e30f;
    float v6 = act ? (dc * a67.x + bb4.z) : -1e30f;
    float v7 = act ? (dc * a67.y + bb4.w) : -1e30f;
    // per-lane max + first-occurrence argmax over this lane's 8 classes
    float m = v0; int aj = 0;
    if (v1 > m) { m = v1; aj = 1; }
    if (v2 > m) { m = v2; aj = 2; }
    if (v3 > m) { m = v3; aj = 3; }
    if (v4 > m) { m = v4; aj = 4; }
    if (v5 > m) { m = v5; aj = 5; }
    if (v6 > m) { m = v6; aj = 6; }
    if (v7 > m) { m = v7; aj = 7; }
    int ac = seg * 8 + aj;
#pragma unroll
    for (int k = 1; k < 8; k <<= 1) {   // reduce within the 8-lane e-group
        float om = __shfl_xor(m, k);
        int oc = __shfl_xor(ac, k);
        if (om > m || (om == m && oc < ac)) { m = om; ac = oc; }
    }
    float s = 0.f;
    if (act) {
        s = expf(v0 - m) + expf(v1 - m) + expf(v2 - m) + expf(v3 - m)
          + expf(v4 - m) + expf(v5 - m) + expf(v6 - m) + expf(v7 - m);
    }
#pragma unroll
    for (int k = 1; k < 8; k <<= 1) s += __shfl_xor(s, k);
    float ls = logf(s);
    if (act) {
        float lp0 = (v0 - m) - ls, lp1 = (v1 - m) - ls, lp2 = (v2 - m) - ls, lp3 = (v3 - m) - ls;
        float lp4 = (v4 - m) - ls, lp5 = (v5 - m) - ls, lp6 = (v6 - m) - ls, lp7 = (v7 - m) - ls;
        float* logp = out + (size_t)node * N_CLASS + seg * 8;
        *(float4*)logp       = make_float4(lp0, lp1, lp2, lp3);
        *(float4*)(logp + 4) = make_float4(lp4, lp5, lp6, lp7);
        float* pp = out + (size_t)N_NODES * N_CLASS + (size_t)node * N_CLASS + seg * 8;
        *(float4*)pp       = make_float4(expf(lp0), expf(lp1), expf(lp2), expf(lp3));
        *(float4*)(pp + 4) = make_float4(expf(lp4), expf(lp5), expf(lp6), expf(lp7));
    }
    if (seg == 0) ps[node] = (unsigned short)((y[node] << 8) | ac);
}

// ---------------- ratio: software-pipelined, ~6 iterations/thread ----------------
#define RATIO_BLOCKS 256
__global__ __launch_bounds__(256) void k_ratio(const int* __restrict__ row, const int* __restrict__ col,
                                               const unsigned short* __restrict__ ps,
                                               unsigned int* __restrict__ cnt) {
    const int G = N_EDGES / 8;
    int i = blockIdx.x * 256 + threadIdx.x;
    int stride = RATIO_BLOCKS * 256;
    unsigned int local = 0;
    int e8 = i;
    if (e8 < G) {
        int4 ra = ((const int4*)row)[e8 * 2];
        int4 rb = ((const int4*)row)[e8 * 2 + 1];
        int4 ca = ((const int4*)col)[e8 * 2];
        int4 cb = ((const int4*)col)[e8 * 2 + 1];
        for (;;) {
            int en = e8 + stride;
            bool more = en < G;
            int4 nra, nrb, nca, ncb;
            if (more) {                      // issue next iteration's edge loads now
                nra = ((const int4*)row)[en * 2];
                nrb = ((const int4*)row)[en * 2 + 1];
                nca = ((const int4*)col)[en * 2];
                ncb = ((const int4*)col)[en * 2 + 1];
            }
            unsigned int pa[8], pb[8];       // 16 independent gathers in flight
            pa[0] = ps[ra.x]; pa[1] = ps[ra.y]; pa[2] = ps[ra.z]; pa[3] = ps[ra.w];
            pa[4] = ps[rb.x]; pa[5] = ps[rb.y]; pa[6] = ps[rb.z]; pa[7] = ps[rb.w];
            pb[0] = ps[ca.x]; pb[1] = ps[ca.y]; pb[2] = ps[ca.z]; pb[3] = ps[ca.w];
            pb[4] = ps[cb.x]; pb[5] = ps[cb.y]; pb[6] = ps[cb.z]; pb[7] = ps[cb.w];
#pragma unroll
            for (int k = 0; k < 8; ++k) {
                bool sp = (pa[k] & 0xffu) == (pb[k] & 0xffu);
                bool sy = (pa[k] >> 8) == (pb[k] >> 8);
                local += (sp == sy) ? 1u : 0u;
            }
            if (!more) break;
            ra = nra; rb = nrb; ca = nca; cb = ncb;
            e8 = en;
        }
    }
    if (local) atomicAdd(cnt, local);
}

__global__ void k_fin(const unsigned int* __restrict__ cnt, float* __restrict__ out) {
    out[0] = (float)(*cnt) / (float)N_EDGES;
}

extern "C" void kernel_launch(void* const* d_in, const int* in_sizes, int n_in,
                              void* d_out, int out_size, void* d_ws, size_t ws_size,
                              hipStream_t stream) {
    const float* x  = (const float*)d_in[0];
    const int*   ei = (const int*)d_in[1];
    const int*   y  = (const int*)d_in[2];
    const float* W1 = (const float*)d_in[3];
    const float* b1 = (const float*)d_in[4];
    const float* W2 = (const float*)d_in[5];
    const float* b2 = (const float*)d_in[6];

    const int* row = ei;
    const int* col = ei + N_EDGES;

    float* ws = (float*)d_ws;
    // workspace layout (4B units); fp8 tables have N_NODES+1 rows (sentinel)
    unsigned char* h1q = (unsigned char*)ws;               // (N+1)*64 B
    unsigned char* h2q = (unsigned char*)(ws + 1700000);   // (N+1)*64 B
    float* dinv   = ws + 3400000;                   // N
    int*   pdeg   = (int*)(ws + 3500000);           // N
    int*   off    = (int*)(ws + 3600000);           // N
    int*   srow   = (int*)(ws + 3700000);           // padded CSR (~4.0M) + tail slack
    int*   ghistT = (int*)(ws + 7800000);           // 256*512 (bucket-major)
    int*   goffT  = (int*)(ws + 8000000);           // 256*512
    int*   tot    = (int*)(ws + 8150000);           // 256
    int*   bbase  = (int*)(ws + 8200000);           // 256
    int*   bend   = (int*)(ws + 8201000);           // 256
    float* pb2    = ws + 8202000;                   // 64 (padded b2)
    unsigned short* ps = (unsigned short*)(ws + 8210000);  // N ushort
    unsigned int* cnt  = (unsigned int*)(ws + 8300000);
    unsigned int* epair = (unsigned int*)(ws + 8400000);   // E uint32 (ends ~11.6M)
    unsigned short* o1b = (unsigned short*)(ws + 11700000); // N*64 bf16 (12.8 MB)

    float* out = (float*)d_out;

    (void)hipMemsetAsync(cnt, 0, 4, stream);

    const int GEMM_GRID = (N_NODES + 63) / 64;      // 1563 blocks, 64 rows each
    const int AGG_GRID = N_NODES / 32;              // 8 nodes/wave * 4 waves = 32 nodes/block

    k_A1<<<NBLK_A, 256, 0, stream>>>(col, ghistT);
    k_A2a<<<256, 256, 0, stream>>>(ghistT, goffT, tot);
    k_A2b<<<1, 256, 0, stream>>>(tot, bbase, bend, h1q, h2q, b2, pb2);
    k_A3<<<NBLK_A, 256, 0, stream>>>(row, col, goffT, bbase, epair);
    k_B<<<NBUCK, 256, 0, stream>>>(epair, bbase, bend, off, pdeg, dinv, srow);
    k_gemm1<<<GEMM_GRID, 256, 0, stream>>>(x, W1, dinv, h1q);
    k_agg1<<<AGG_GRID, 256, 0, stream>>>(off, pdeg, srow, dinv, h1q, b1, o1b);
    k_gemm2<<<GEMM_GRID, 256, 0, stream>>>(o1b, W2, h2q);
    k_agg2<<<AGG_GRID, 256, 0, stream>>>(off, pdeg, srow, dinv, h2q, pb2, y, out, ps);
    k_ratio<<<RATIO_BLOCKS, 256, 0, stream>>>(row, col, ps, cnt);
    k_fin<<<1, 1, 0, stream>>>(cnt, out + (size_t)2 * N_NODES * N_CLASS);
}

// Round 25
// 263.098 us; speedup vs baseline: 1.5919x; 1.0434x over previous
//
#include <hip/hip_runtime.h>

#define N_NODES 100000
#define N_EDGES 3200000
#define F_IN 128
#define HID 64
#define N_CLASS 40
#define ZROW N_NODES       // sentinel zero-row index

#define NBUCK 196          // ceil(100000/512)
#define BSHIFT 9
#define NBLK_A 512
#define CHUNK_A ((N_EDGES + NBLK_A - 1) / NBLK_A)

typedef float f32x2 __attribute__((ext_vector_type(2)));
typedef __attribute__((ext_vector_type(8))) short bf16x8;
typedef __attribute__((ext_vector_type(4))) float f32x4v;

static __device__ __forceinline__ unsigned char enc_fp8(float v) {
    return (unsigned char)(__builtin_amdgcn_cvt_pk_fp8_f32(v, v, 0, false) & 0xff);
}
static __device__ __forceinline__ unsigned cvtpk_bf16(float lo, float hi) {
    unsigned r;
    asm("v_cvt_pk_bf16_f32 %0, %1, %2" : "=v"(r) : "v"(lo), "v"(hi));
    return r;
}

// gather 8 fp8 bytes: byteoff = row<<6 (pre-shifted), seg in [0,8)
static __device__ __forceinline__ uint2 gat8(const unsigned char* base, int byteoff, int seg) {
    return *(const uint2*)(base + ((unsigned)byteoff | (unsigned)(seg << 3)));
}

// decode 8 fp8 (uint2), packed-f32 accumulate
#define CONS(RAW) do { \
    f32x2 f0 = __builtin_amdgcn_cvt_pk_f32_fp8((int)RAW.x, false); \
    f32x2 f1 = __builtin_amdgcn_cvt_pk_f32_fp8((int)RAW.x, true); \
    f32x2 f2 = __builtin_amdgcn_cvt_pk_f32_fp8((int)RAW.y, false); \
    f32x2 f3 = __builtin_amdgcn_cvt_pk_f32_fp8((int)RAW.y, true); \
    a01 += f0; a23 += f1; a45 += f2; a67 += f3; } while (0)

// 6-deep pipelined slot: consume G (edge bb+s of MY node), issue edge bb+6+s,
// reload C with idx for edge bb+12+s (address clamped to my range)
#define SLOTP(s, G, C) { \
    int ib = bb + 6 + s; \
    int srcr = (ib < mydeg) ? C : zb; \
    uint2 ng = gat8(gsrc, srcr, seg); \
    C = sp[min(bb + 12 + s, mlast)]; \
    __builtin_amdgcn_sched_barrier(0); \
    CONS(G); \
    G = ng; }

// per-lane gather phase: each lane owns node `node` (e-group) and features seg*8..+7.
#define GATHER_PL(TBL) \
    f32x2 a01 = {0.f, 0.f}, a23 = {0.f, 0.f}, a45 = {0.f, 0.f}, a67 = {0.f, 0.f}; \
    { \
        const unsigned char* gsrc = TBL; \
        const int* sp = srow + myoff; \
        const int zb = ZROW << 6; \
        int nbmax = mydeg; \
        nbmax = max(nbmax, __shfl_xor(nbmax, 8)); \
        nbmax = max(nbmax, __shfl_xor(nbmax, 16)); \
        nbmax = max(nbmax, __shfl_xor(nbmax, 32)); \
        if (nbmax > 0) { \
            int mlast = mydeg > 0 ? mydeg - 1 : 0; \
            uint2 g0 = gat8(gsrc, (0 < mydeg) ? sp[0] : zb, seg); \
            uint2 g1 = gat8(gsrc, (1 < mydeg) ? sp[min(1, mlast)] : zb, seg); \
            uint2 g2 = gat8(gsrc, (2 < mydeg) ? sp[min(2, mlast)] : zb, seg); \
            uint2 g3 = gat8(gsrc, (3 < mydeg) ? sp[min(3, mlast)] : zb, seg); \
            uint2 g4 = gat8(gsrc, (4 < mydeg) ? sp[min(4, mlast)] : zb, seg); \
            uint2 g5 = gat8(gsrc, (5 < mydeg) ? sp[min(5, mlast)] : zb, seg); \
            int c0 = sp[min(6, mlast)],  c1 = sp[min(7, mlast)],  c2 = sp[min(8, mlast)]; \
            int c3 = sp[min(9, mlast)], c4 = sp[min(10, mlast)], c5 = sp[min(11, mlast)]; \
            for (int bb = 0; bb < nbmax; bb += 6) { \
                SLOTP(0, g0, c0) SLOTP(1, g1, c1) SLOTP(2, g2, c2) \
                SLOTP(3, g3, c3) SLOTP(4, g4, c4) SLOTP(5, g5, c5) \
            } \
        } \
        /* self term: every lane adds its own node's segment once */ \
        uint2 sg = gat8(gsrc, node << 6, seg); \
        CONS(sg); \
    }

// ---------------- Phase A1: per-block bucket histogram (transposed out) ----------------
__global__ __launch_bounds__(256) void k_A1(const int* __restrict__ col, int* __restrict__ ghistT) {
    __shared__ int hist[256];
    int t = threadIdx.x;
    hist[t] = 0;
    __syncthreads();
    int e0 = blockIdx.x * CHUNK_A;
    int e1 = e0 + CHUNK_A; if (e1 > N_EDGES) e1 = N_EDGES;
    for (int e = e0 + t; e < e1; e += 256) {
        atomicAdd(&hist[col[e] >> BSHIFT], 1);
    }
    __syncthreads();
    ghistT[t * NBLK_A + blockIdx.x] = hist[t];
}

// ---------------- Phase A2a: per-bucket scan over 512 A-blocks ----------------
__global__ __launch_bounds__(256) void k_A2a(const int* __restrict__ ghistT, int* __restrict__ goffT,
                                             int* __restrict__ tot) {
    __shared__ int s[256];
    int b = blockIdx.x, t = threadIdx.x;
    int2 v = ((const int2*)(ghistT + b * NBLK_A))[t];
    int pair = v.x + v.y;
    s[t] = pair;
    __syncthreads();
    for (int d = 1; d < 256; d <<= 1) {
        int o = (t >= d) ? s[t - d] : 0;
        __syncthreads();
        s[t] += o;
        __syncthreads();
    }
    int incl = s[t];
    int excl = incl - pair;
    goffT[b * NBLK_A + 2 * t]     = excl;
    goffT[b * NBLK_A + 2 * t + 1] = excl + v.x;
    if (t == 255) tot[b] = incl;
}

// ---------------- Phase A2b: scan of bucket totals + sentinel zero + padded b2 ----------------
__global__ __launch_bounds__(256) void k_A2b(const int* __restrict__ tot, int* __restrict__ bbase,
                                             int* __restrict__ bend,
                                             unsigned char* __restrict__ h1q,
                                             unsigned char* __restrict__ h2q,
                                             const float* __restrict__ b2, float* __restrict__ pb2) {
    __shared__ int s[256];
    int t = threadIdx.x;
    int v = tot[t];
    s[t] = v;
    __syncthreads();
    for (int d = 1; d < 256; d <<= 1) {
        int o = (t >= d) ? s[t - d] : 0;
        __syncthreads();
        s[t] += o;
        __syncthreads();
    }
    bbase[t] = s[t] - v;
    bend[t] = s[t];
    if (t < 64) h1q[(size_t)ZROW * 64 + t] = 0;
    else if (t < 128) h2q[(size_t)ZROW * 64 + (t - 64)] = 0;
    else if (t < 192) pb2[t - 128] = (t - 128 < N_CLASS) ? b2[t - 128] : 0.f;
}

// ---------------- Phase A3: coalesced-reserved bucket scatter ----------------
__global__ __launch_bounds__(256) void k_A3(const int* __restrict__ row, const int* __restrict__ col,
                                            const int* __restrict__ goffT, const int* __restrict__ bbase,
                                            unsigned int* __restrict__ epair) {
    __shared__ int cur[256];
    int t = threadIdx.x;
    cur[t] = goffT[t * NBLK_A + blockIdx.x] + bbase[t];
    __syncthreads();
    int e0 = blockIdx.x * CHUNK_A;
    int e1 = e0 + CHUNK_A; if (e1 > N_EDGES) e1 = N_EDGES;
    for (int e = e0 + t; e < e1; e += 256) {
        int c = col[e];
        int pos = atomicAdd(&cur[c >> BSHIFT], 1);
        epair[pos] = ((unsigned int)(c & 511) << 17) | (unsigned int)row[e];
    }
}

// ---------------- Phase B: per-bucket CSR build; srow holds (row<<6) byte offsets ----------------
__global__ __launch_bounds__(256) void k_B(const unsigned int* __restrict__ epair,
                                           const int* __restrict__ bbase, const int* __restrict__ bend,
                                           int* __restrict__ off, int* __restrict__ pdeg,
                                           float* __restrict__ dinv, int* __restrict__ srow) {
    __shared__ int h[512];
    __shared__ int psc[256];
    int t = threadIdx.x;
    int b = blockIdx.x;
    int n0 = b << BSHIFT;
    int e0 = bbase[b], e1 = bend[b];
    int pbase = e0 + b * 4096;
    h[t] = 0; h[t + 256] = 0;
    __syncthreads();
    for (int e = e0 + t; e < e1; e += 256) {
        atomicAdd(&h[epair[e] >> 17], 1);
    }
    __syncthreads();
    int a0 = h[2 * t], a1 = h[2 * t + 1];
    int p0 = (a0 + 7) & ~7, p1 = (a1 + 7) & ~7;
    psc[t] = p0 + p1;
    __syncthreads();
    for (int d = 1; d < 256; d <<= 1) {
        int o = (t >= d) ? psc[t - d] : 0;
        __syncthreads();
        psc[t] += o;
        __syncthreads();
    }
    int base0 = pbase + psc[t] - (p0 + p1);
    int base1 = base0 + p0;
    h[2 * t] = base0;
    h[2 * t + 1] = base1;
    int n = n0 + 2 * t;
    const int zb = ZROW << 6;
    if (n < N_NODES) {
        off[n] = base0; pdeg[n] = p0; dinv[n] = rsqrtf((float)a0 + 1.0f);
        for (int p = a0; p < p0; ++p) srow[base0 + p] = zb;
    }
    if (n + 1 < N_NODES) {
        off[n + 1] = base1; pdeg[n + 1] = p1; dinv[n + 1] = rsqrtf((float)a1 + 1.0f);
        for (int p = a1; p < p1; ++p) srow[base1 + p] = zb;
    }
    __syncthreads();
    for (int e = e0 + t; e < e1; e += 256) {
        unsigned int k = epair[e];
        int c = k >> 17;
        int pos = atomicAdd(&h[c], 1);
        srow[pos] = (int)(k & 0x1FFFFu) << 6;
    }
}

// ---------------- layer-1 GEMM via MFMA bf16: h1q = fp8(dinv[n] * (X @ W1^T)) ----------------
#define LDB1(CT, KK, VAR) { \
    int n = CT * 16 + m; \
    const float4* p = (const float4*)W + ((size_t)n * 32 + KK * 8 + g * 2); \
    float4 v0 = p[0], v1 = p[1]; \
    uint4 u; \
    u.x = cvtpk_bf16(v0.x, v0.y); u.y = cvtpk_bf16(v0.z, v0.w); \
    u.z = cvtpk_bf16(v1.x, v1.y); u.w = cvtpk_bf16(v1.z, v1.w); \
    VAR = *(bf16x8*)&u; }

#define STEP1(KK, B0, B1, B2, B3) { \
    float4 v0 = make_float4(0.f,0.f,0.f,0.f), v1 = make_float4(0.f,0.f,0.f,0.f); \
    if (ar < N_NODES) { \
        const float4* p = (const float4*)X + ((size_t)ar * 32 + KK * 8 + g * 2); \
        v0 = p[0]; v1 = p[1]; \
    } \
    uint4 u; \
    u.x = cvtpk_bf16(v0.x, v0.y); u.y = cvtpk_bf16(v0.z, v0.w); \
    u.z = cvtpk_bf16(v1.x, v1.y); u.w = cvtpk_bf16(v1.z, v1.w); \
    bf16x8 af = *(bf16x8*)&u; \
    ac0 = __builtin_amdgcn_mfma_f32_16x16x32_bf16(af, B0, ac0, 0, 0, 0); \
    ac1 = __builtin_amdgcn_mfma_f32_16x16x32_bf16(af, B1, ac1, 0, 0, 0); \
    ac2 = __builtin_amdgcn_mfma_f32_16x16x32_bf16(af, B2, ac2, 0, 0, 0); \
    ac3 = __builtin_amdgcn_mfma_f32_16x16x32_bf16(af, B3, ac3, 0, 0, 0); }

__global__ __launch_bounds__(256) void k_gemm1(const float* __restrict__ X, const float* __restrict__ W,
                                               const float* __restrict__ scale, unsigned char* __restrict__ O) {
    int t = threadIdx.x;
    int lane = t & 63, w = t >> 6;
    int m = lane & 15, g = lane >> 4;
    bf16x8 b00, b01, b02, b03, b10, b11, b12, b13, b20, b21, b22, b23, b30, b31, b32, b33;
    LDB1(0,0,b00) LDB1(0,1,b01) LDB1(0,2,b02) LDB1(0,3,b03)
    LDB1(1,0,b10) LDB1(1,1,b11) LDB1(1,2,b12) LDB1(1,3,b13)
    LDB1(2,0,b20) LDB1(2,1,b21) LDB1(2,2,b22) LDB1(2,3,b23)
    LDB1(3,0,b30) LDB1(3,1,b31) LDB1(3,2,b32) LDB1(3,3,b33)
    int rb = blockIdx.x * 64 + w * 16;
    int ar = rb + m;   // A row this lane loads
    f32x4v ac0 = {0.f,0.f,0.f,0.f}, ac1 = {0.f,0.f,0.f,0.f};
    f32x4v ac2 = {0.f,0.f,0.f,0.f}, ac3 = {0.f,0.f,0.f,0.f};
    STEP1(0, b00, b10, b20, b30)
    STEP1(1, b01, b11, b21, b31)
    STEP1(2, b02, b12, b22, b32)
    STEP1(3, b03, b13, b23, b33)
#pragma unroll
    for (int r = 0; r < 4; ++r) {
        int rr = rb + g * 4 + r;
        if (rr < N_NODES) {
            float sc = scale[rr];
            O[(size_t)rr * 64 +      m] = enc_fp8(ac0[r] * sc);
            O[(size_t)rr * 64 + 16 + m] = enc_fp8(ac1[r] * sc);
            O[(size_t)rr * 64 + 32 + m] = enc_fp8(ac2[r] * sc);
            O[(size_t)rr * 64 + 48 + m] = enc_fp8(ac3[r] * sc);
        }
    }
}

// ---------------- layer-2 GEMM via MFMA bf16: h2q = fp8(8 * (o1b @ W2^T)) ----------------
#define LDB2(CT, KK, VAR) { \
    int n = CT * 16 + m; \
    float4 v0 = make_float4(0.f,0.f,0.f,0.f), v1 = make_float4(0.f,0.f,0.f,0.f); \
    if (n < N_CLASS) { \
        const float4* p = (const float4*)W2 + ((size_t)n * 16 + KK * 8 + g * 2); \
        v0 = p[0]; v1 = p[1]; \
    } \
    uint4 u; \
    u.x = cvtpk_bf16(v0.x * 8.f, v0.y * 8.f); u.y = cvtpk_bf16(v0.z * 8.f, v0.w * 8.f); \
    u.z = cvtpk_bf16(v1.x * 8.f, v1.y * 8.f); u.w = cvtpk_bf16(v1.z * 8.f, v1.w * 8.f); \
    VAR = *(bf16x8*)&u; }

#define STEP2(KK, B0, B1, B2, B3) { \
    uint4 u = make_uint4(0u,0u,0u,0u); \
    if (ar < N_NODES) u = *(const uint4*)(o1b + ((size_t)ar * 64 + KK * 32 + g * 8)); \
    bf16x8 af = *(bf16x8*)&u; \
    ac0 = __builtin_amdgcn_mfma_f32_16x16x32_bf16(af, B0, ac0, 0, 0, 0); \
    ac1 = __builtin_amdgcn_mfma_f32_16x16x32_bf16(af, B1, ac1, 0, 0, 0); \
    ac2 = __builtin_amdgcn_mfma_f32_16x16x32_bf16(af, B2, ac2, 0, 0, 0); \
    ac3 = __builtin_amdgcn_mfma_f32_16x16x32_bf16(af, B3, ac3, 0, 0, 0); }

__global__ __launch_bounds__(256) void k_gemm2(const unsigned short* __restrict__ o1b,
                                               const float* __restrict__ W2,
                                               unsigned char* __restrict__ h2q) {
    int t = threadIdx.x;
    int lane = t & 63, w = t >> 6;
    int m = lane & 15, g = lane >> 4;
    bf16x8 b00, b01, b10, b11, b20, b21, b30, b31;
    LDB2(0,0,b00) LDB2(0,1,b01) LDB2(1,0,b10) LDB2(1,1,b11)
    LDB2(2,0,b20) LDB2(2,1,b21) LDB2(3,0,b30) LDB2(3,1,b31)
    int rb = blockIdx.x * 64 + w * 16;
    int ar = rb + m;
    f32x4v ac0 = {0.f,0.f,0.f,0.f}, ac1 = {0.f,0.f,0.f,0.f};
    f32x4v ac2 = {0.f,0.f,0.f,0.f}, ac3 = {0.f,0.f,0.f,0.f};
    STEP2(0, b00, b10, b20, b30)
    STEP2(1, b01, b11, b21, b31)
#pragma unroll
    for (int r = 0; r < 4; ++r) {
        int rr = rb + g * 4 + r;
        if (rr < N_NODES) {
            h2q[(size_t)rr * 64 +      m] = enc_fp8(ac0[r]);
            h2q[(size_t)rr * 64 + 16 + m] = enc_fp8(ac1[r]);
            h2q[(size_t)rr * 64 + 32 + m] = enc_fp8(ac2[r]);
            h2q[(size_t)rr * 64 + 48 + m] = enc_fp8(ac3[r]);
        }
    }
}

// ---------------- layer-1 aggregation: 8 nodes/wave -> o1b bf16 ----------------
__global__ __launch_bounds__(256) void k_agg1(const int* __restrict__ off, const int* __restrict__ pdeg,
                                              const int* __restrict__ srow, const float* __restrict__ dinv,
                                              const unsigned char* __restrict__ h1q, const float* __restrict__ b1,
                                              unsigned short* __restrict__ o1b) {
    int t = threadIdx.x;
    int lane = t & 63;
    int e = lane >> 3, seg = lane & 7;
    int node = ((blockIdx.x * 256 + t) >> 6) * 8 + e;   // 8 consecutive nodes per wave
    int myoff = off[node];
    int mydeg = pdeg[node];
    GATHER_PL(h1q)
    float dc = dinv[node];
    float4 ba = *(const float4*)(b1 + seg * 8);
    float4 bb4 = *(const float4*)(b1 + seg * 8 + 4);
    float v0 = dc * a01.x + ba.x,  v1 = dc * a01.y + ba.y;
    float v2 = dc * a23.x + ba.z,  v3 = dc * a23.y + ba.w;
    float v4 = dc * a45.x + bb4.x, v5 = dc * a45.y + bb4.y;
    float v6 = dc * a67.x + bb4.z, v7 = dc * a67.y + bb4.w;
    v0 = v0 > 0.f ? v0 * dc : 0.f; v1 = v1 > 0.f ? v1 * dc : 0.f;
    v2 = v2 > 0.f ? v2 * dc : 0.f; v3 = v3 > 0.f ? v3 * dc : 0.f;
    v4 = v4 > 0.f ? v4 * dc : 0.f; v5 = v5 > 0.f ? v5 * dc : 0.f;
    v6 = v6 > 0.f ? v6 * dc : 0.f; v7 = v7 > 0.f ? v7 * dc : 0.f;
    uint4 pk;
    pk.x = cvtpk_bf16(v0, v1); pk.y = cvtpk_bf16(v2, v3);
    pk.z = cvtpk_bf16(v4, v5); pk.w = cvtpk_bf16(v6, v7);
    *(uint4*)(o1b + ((size_t)node * 64 + seg * 8)) = pk;
}

// ---------------- layer-2 aggregation: 8 nodes/wave + per-group softmax/argmax ----------------
__global__ __launch_bounds__(256) void k_agg2(const int* __restrict__ off, const int* __restrict__ pdeg,
                                              const int* __restrict__ srow, const float* __restrict__ dinv,
                                              const unsigned char* __restrict__ h2q,
                                              const float* __restrict__ pb2, const int* __restrict__ y,
                                              float* __restrict__ out, unsigned short* __restrict__ ps) {
    int t = threadIdx.x;
    int lane = t & 63;
    int e = lane >> 3, seg = lane & 7;
    int node = ((blockIdx.x * 256 + t) >> 6) * 8 + e;
    int myoff = off[node];
    int mydeg = pdeg[node];
    GATHER_PL(h2q)
    float dc = dinv[node] * 0.125f;   // undo the x8 h2q scale
    float4 ba = *(const float4*)(pb2 + seg * 8);
    float4 bb4 = *(const float4*)(pb2 + seg * 8 + 4);
    bool act = seg < 5;               // classes seg*8..seg*8+7, 40 = 5*8
    float v0 = act ? (dc * a01.x + ba.x)  : -1e30f;
    float v1 = act ? (dc * a01.y + ba.y)  : -1e30f;
    float v2 = act ? (dc * a23.x + ba.z)  : -1e30f;
    float v3 = act ? (dc * a23.y + ba.w)  : -1e30f;
    float v4 = act ? (dc * a45.x + bb4.x) : -1e30f;
    float v5 = act ? (dc * a45.y + bb4.y) : -1e30f;
    float v6 = act ? (dc * a67.x + bb4.z) : -1e30f;
    float v7 = act ? (dc * a67.y + bb4.w) : -1e30f;
    // per-lane max + first-occurrence argmax over this lane's 8 classes
    float m = v0; int aj = 0;
    if (v1 > m) { m = v1; aj = 1; }
    if (v2 > m) { m = v2; aj = 2; }
    if (v3 > m) { m = v3; aj = 3; }
    if (v4 > m) { m = v4; aj = 4; }
    if (v5 > m) { m = v5; aj = 5; }
    if (v6 > m) { m = v6; aj = 6; }
    if (v7 > m) { m = v7; aj = 7; }
    int ac = seg * 8 + aj;
#pragma unroll
    for (int k = 1; k < 8; k <<= 1) {   // reduce within the 8-lane e-group
        float om = __shfl_xor(m, k);
        int oc = __shfl_xor(ac, k);
        if (om > m || (om == m && oc < ac)) { m = om; ac = oc; }
    }
    float s = 0.f;
    if (act) {
        s = expf(v0 - m) + expf(v1 - m) + expf(v2 - m) + expf(v3 - m)
          + expf(v4 - m) + expf(v5 - m) + expf(v6 - m) + expf(v7 - m);
    }
#pragma unroll
    for (int k = 1; k < 8; k <<= 1) s += __shfl_xor(s, k);
    float ls = logf(s);
    if (act) {
        float lp0 = (v0 - m) - ls, lp1 = (v1 - m) - ls, lp2 = (v2 - m) - ls, lp3 = (v3 - m) - ls;
        float lp4 = (v4 - m) - ls, lp5 = (v5 - m) - ls, lp6 = (v6 - m) - ls, lp7 = (v7 - m) - ls;
        float* logp = out + (size_t)node * N_CLASS + seg * 8;
        *(float4*)logp       = make_float4(lp0, lp1, lp2, lp3);
        *(float4*)(logp + 4) = make_float4(lp4, lp5, lp6, lp7);
        float* pp = out + (size_t)N_NODES * N_CLASS + (size_t)node * N_CLASS + seg * 8;
        *(float4*)pp       = make_float4(expf(lp0), expf(lp1), expf(lp2), expf(lp3));
        *(float4*)(pp + 4) = make_float4(expf(lp4), expf(lp5), expf(lp6), expf(lp7));
    }
    if (seg == 0) ps[node] = (unsigned short)((y[node] << 8) | ac);
}

// ---------------- ratio + finalize (completion-ticket), ~6 pipelined iters/thread ----------------
#define RATIO_BLOCKS 256
__global__ __launch_bounds__(256) void k_ratio(const int* __restrict__ row, const int* __restrict__ col,
                                               const unsigned short* __restrict__ ps,
                                               unsigned int* __restrict__ cnt, float* __restrict__ outr) {
    __shared__ unsigned int sred[256];
    const int G = N_EDGES / 8;
    int i = blockIdx.x * 256 + threadIdx.x;
    int stride = RATIO_BLOCKS * 256;
    unsigned int local = 0;
    int e8 = i;
    if (e8 < G) {
        int4 ra = ((const int4*)row)[e8 * 2];
        int4 rb = ((const int4*)row)[e8 * 2 + 1];
        int4 ca = ((const int4*)col)[e8 * 2];
        int4 cb = ((const int4*)col)[e8 * 2 + 1];
        for (;;) {
            int en = e8 + stride;
            bool more = en < G;
            int4 nra, nrb, nca, ncb;
            if (more) {                      // issue next iteration's edge loads now
                nra = ((const int4*)row)[en * 2];
                nrb = ((const int4*)row)[en * 2 + 1];
                nca = ((const int4*)col)[en * 2];
                ncb = ((const int4*)col)[en * 2 + 1];
            }
            unsigned int pa[8], pb[8];       // 16 independent gathers in flight
            pa[0] = ps[ra.x]; pa[1] = ps[ra.y]; pa[2] = ps[ra.z]; pa[3] = ps[ra.w];
            pa[4] = ps[rb.x]; pa[5] = ps[rb.y]; pa[6] = ps[rb.z]; pa[7] = ps[rb.w];
            pb[0] = ps[ca.x]; pb[1] = ps[ca.y]; pb[2] = ps[ca.z]; pb[3] = ps[ca.w];
            pb[4] = ps[cb.x]; pb[5] = ps[cb.y]; pb[6] = ps[cb.z]; pb[7] = ps[cb.w];
#pragma unroll
            for (int k = 0; k < 8; ++k) {
                bool sp = (pa[k] & 0xffu) == (pb[k] & 0xffu);
                bool sy = (pa[k] >> 8) == (pb[k] >> 8);
                local += (sp == sy) ? 1u : 0u;
            }
            if (!more) break;
            ra = nra; rb = nrb; ca = nca; cb = ncb;
            e8 = en;
        }
    }
    sred[threadIdx.x] = local;
    __syncthreads();
    for (int d = 128; d > 0; d >>= 1) {
        if (threadIdx.x < d) sred[threadIdx.x] += sred[threadIdx.x + d];
        __syncthreads();
    }
    if (threadIdx.x == 0) {
        unsigned int* tick = cnt + 1;
        atomicAdd(cnt, sred[0]);
        __threadfence();
        unsigned int tk = atomicAdd(tick, 1u);
        if (tk == RATIO_BLOCKS - 1) {        // last block: all cnt adds are visible
            unsigned int total = atomicAdd(cnt, 0u);
            outr[0] = (float)total / (float)N_EDGES;
        }
    }
}

extern "C" void kernel_launch(void* const* d_in, const int* in_sizes, int n_in,
                              void* d_out, int out_size, void* d_ws, size_t ws_size,
                              hipStream_t stream) {
    const float* x  = (const float*)d_in[0];
    const int*   ei = (const int*)d_in[1];
    const int*   y  = (const int*)d_in[2];
    const float* W1 = (const float*)d_in[3];
    const float* b1 = (const float*)d_in[4];
    const float* W2 = (const float*)d_in[5];
    const float* b2 = (const float*)d_in[6];

    const int* row = ei;
    const int* col = ei + N_EDGES;

    float* ws = (float*)d_ws;
    // workspace layout (4B units); fp8 tables have N_NODES+1 rows (sentinel)
    unsigned char* h1q = (unsigned char*)ws;               // (N+1)*64 B
    unsigned char* h2q = (unsigned char*)(ws + 1700000);   // (N+1)*64 B
    float* dinv   = ws + 3400000;                   // N
    int*   pdeg   = (int*)(ws + 3500000);           // N
    int*   off    = (int*)(ws + 3600000);           // N
    int*   srow   = (int*)(ws + 3700000);           // padded CSR (~4.0M) + tail slack
    int*   ghistT = (int*)(ws + 7800000);           // 256*512 (bucket-major)
    int*   goffT  = (int*)(ws + 8000000);           // 256*512
    int*   tot    = (int*)(ws + 8150000);           // 256
    int*   bbase  = (int*)(ws + 8200000);           // 256
    int*   bend   = (int*)(ws + 8201000);           // 256
    float* pb2    = ws + 8202000;                   // 64 (padded b2)
    unsigned short* ps = (unsigned short*)(ws + 8210000);  // N ushort
    unsigned int* cnt  = (unsigned int*)(ws + 8300000);    // [0]=count, [1]=ticket
    unsigned int* epair = (unsigned int*)(ws + 8400000);   // E uint32 (ends ~11.6M)
    unsigned short* o1b = (unsigned short*)(ws + 11700000); // N*64 bf16 (12.8 MB)

    float* out = (float*)d_out;

    (void)hipMemsetAsync(cnt, 0, 8, stream);   // count + ticket

    const int GEMM_GRID = (N_NODES + 63) / 64;      // 1563 blocks, 64 rows each
    const int AGG_GRID = N_NODES / 32;              // 8 nodes/wave * 4 waves = 32 nodes/block

    k_A1<<<NBLK_A, 256, 0, stream>>>(col, ghistT);
    k_A2a<<<256, 256, 0, stream>>>(ghistT, goffT, tot);
    k_A2b<<<1, 256, 0, stream>>>(tot, bbase, bend, h1q, h2q, b2, pb2);
    k_A3<<<NBLK_A, 256, 0, stream>>>(row, col, goffT, bbase, epair);
    k_B<<<NBUCK, 256, 0, stream>>>(epair, bbase, bend, off, pdeg, dinv, srow);
    k_gemm1<<<GEMM_GRID, 256, 0, stream>>>(x, W1, dinv, h1q);
    k_agg1<<<AGG_GRID, 256, 0, stream>>>(off, pdeg, srow, dinv, h1q, b1, o1b);
    k_gemm2<<<GEMM_GRID, 256, 0, stream>>>(o1b, W2, h2q);
    k_agg2<<<AGG_GRID, 256, 0, stream>>>(off, pdeg, srow, dinv, h2q, pb2, y, out, ps);
    k_ratio<<<RATIO_BLOCKS, 256, 0, stream>>>(row, col, ps, cnt, out + (size_t)2 * N_NODES * N_CLASS);
}